// Round 1
// baseline (1796.319 us; speedup 1.0000x reference)
//
#include <hip/hip_runtime.h>
#include <math.h>

#define BN_EPS 1e-5f
#define GBM 64
#define GBN 64
#define GBK 16

// ---------- edge-index layout detection (int32 vs int64 storage) ----------
// int64 little-endian with values < 2^31: odd 32-bit words are all zero.
__global__ __launch_bounds__(256)
void k_detect(const unsigned int* __restrict__ ei, int n_check, int* __restrict__ flag) {
    __shared__ int any;
    if (threadIdx.x == 0) any = 0;
    __syncthreads();
    for (int i = threadIdx.x; i < n_check; i += 256) {
        if (ei[2 * i + 1] != 0u) any = 1;   // benign race: all writers store 1
    }
    __syncthreads();
    if (threadIdx.x == 0) *flag = any;      // 1 => int32 layout, 0 => int64 layout
}

__global__ __launch_bounds__(256)
void k_convert(const void* __restrict__ ei_raw, const int* __restrict__ flag,
               int* __restrict__ src, int* __restrict__ dst, int E) {
    int e = blockIdx.x * 256 + threadIdx.x;
    if (e >= E) return;
    if (*flag) {
        const int* a = (const int*)ei_raw;
        src[e] = a[e];
        dst[e] = a[E + e];
    } else {
        const long long* a = (const long long*)ei_raw;
        src[e] = (int)a[e];
        dst[e] = (int)a[E + e];
    }
}

// ---------- degree histogram ----------
__global__ __launch_bounds__(256)
void k_count(const int* __restrict__ dst, int* __restrict__ cnt, int E) {
    int e = blockIdx.x * 256 + threadIdx.x;
    if (e < E) atomicAdd(&cnt[dst[e]], 1);
}

// ---------- single-block exclusive scan over N counts -> row_ptr, cursor, dinv ----------
__global__ __launch_bounds__(1024)
void k_scan(const int* __restrict__ cnt, int* __restrict__ row_ptr, int* __restrict__ cursor,
            float* __restrict__ dinv, int N) {
    __shared__ int sdata[1024];
    __shared__ int carry_s;
    int t = threadIdx.x;
    if (t == 0) carry_s = 0;
    __syncthreads();
    for (int base = 0; base < N; base += 1024) {
        int i = base + t;
        int v = (i < N) ? cnt[i] : 0;
        sdata[t] = v;
        __syncthreads();
        for (int off = 1; off < 1024; off <<= 1) {
            int tmp = (t >= off) ? sdata[t - off] : 0;
            __syncthreads();
            sdata[t] += tmp;
            __syncthreads();
        }
        int incl  = sdata[t];
        int total = sdata[1023];
        int c = carry_s;
        if (i < N) {
            int excl = c + incl - v;
            row_ptr[i] = excl;
            cursor[i]  = excl;
            dinv[i] = rsqrtf((float)(v + 1));   // +1 self-loop
        }
        __syncthreads();
        if (t == 0) carry_s = c + total;
        __syncthreads();
    }
    if (t == 0) row_ptr[N] = carry_s;
}

// ---------- CSR fill with per-edge weight dinv[src]*dinv[dst] ----------
__global__ __launch_bounds__(256)
void k_fill(const int* __restrict__ src, const int* __restrict__ dst,
            int* __restrict__ cursor, const float* __restrict__ dinv,
            int* __restrict__ csr_src, float* __restrict__ csr_w, int E) {
    int e = blockIdx.x * 256 + threadIdx.x;
    if (e >= E) return;
    int s = src[e], d = dst[e];
    int p = atomicAdd(&cursor[d], 1);
    csr_src[p] = s;
    csr_w[p]   = dinv[s] * dinv[d];
}

// ---------- batchnorm column stats (sum, sumsq) ----------
__global__ __launch_bounds__(256)
void k_bnstats(const float* __restrict__ x, float* __restrict__ sum, float* __restrict__ sumsq,
               int N, int F, int rows_per_chunk) {
    int c = blockIdx.x * 256 + threadIdx.x;
    if (c >= F) return;
    int r0 = blockIdx.y * rows_per_chunk;
    int r1 = min(r0 + rows_per_chunk, N);
    float s = 0.f, ss = 0.f;
    for (int r = r0; r < r1; ++r) {
        float v = x[(size_t)r * F + c];
        s += v; ss += v * v;
    }
    atomicAdd(&sum[c], s);
    atomicAdd(&sumsq[c], ss);
}

__global__ __launch_bounds__(256)
void k_bnfin(const float* __restrict__ sum, const float* __restrict__ sumsq,
             const float* __restrict__ gamma, const float* __restrict__ beta,
             float* __restrict__ a, float* __restrict__ b, int N, int F) {
    int c = blockIdx.x * 256 + threadIdx.x;
    if (c >= F) return;
    float m   = sum[c] / (float)N;
    float var = sumsq[c] / (float)N - m * m;
    float rs  = rsqrtf(var + BN_EPS);
    float aa  = gamma[c] * rs;
    a[c] = aa;
    b[c] = beta[c] - m * aa;
}

// ---------- fp32 tiled GEMM: C[M,NC] = f(A[M,K]) @ W[K,NC], f = optional per-k affine ----------
__global__ __launch_bounds__(256)
void k_gemm(const float* __restrict__ A, const float* __restrict__ W,
            float* __restrict__ C, int M, int K, int NC,
            const float* __restrict__ bn_a, const float* __restrict__ bn_b) {
    __shared__ float As[GBK][GBM];
    __shared__ float Ws[GBK][GBN];
    int t  = threadIdx.x;
    int lm = t >> 2;             // A-load row in tile 0..63
    int lk = (t & 3) << 2;       // A-load k offset 0,4,8,12
    int wk = t >> 4;             // W-load k 0..15
    int wn = (t & 15) << 2;      // W-load col 0..60
    int row = blockIdx.x * GBM + lm;
    bool rowok = row < M;
    const float* Ap = A + (size_t)row * K + lk;
    const float* Wp = W + (size_t)wk * NC + blockIdx.y * GBN + wn;
    int tm = (t & 15) << 2;      // micro-tile rows
    int tn = (t >> 4) << 2;      // micro-tile cols
    float acc[4][4];
    #pragma unroll
    for (int i = 0; i < 4; i++)
        #pragma unroll
        for (int j = 0; j < 4; j++) acc[i][j] = 0.f;

    for (int k0 = 0; k0 < K; k0 += GBK) {
        float4 av = make_float4(0.f, 0.f, 0.f, 0.f);
        if (rowok) av = *(const float4*)(Ap + k0);
        if (bn_a) {
            int kb = k0 + lk;
            av.x = av.x * bn_a[kb + 0] + bn_b[kb + 0];
            av.y = av.y * bn_a[kb + 1] + bn_b[kb + 1];
            av.z = av.z * bn_a[kb + 2] + bn_b[kb + 2];
            av.w = av.w * bn_a[kb + 3] + bn_b[kb + 3];
        }
        float4 wv = *(const float4*)(Wp + (size_t)k0 * NC);
        __syncthreads();
        As[lk + 0][lm] = av.x;
        As[lk + 1][lm] = av.y;
        As[lk + 2][lm] = av.z;
        As[lk + 3][lm] = av.w;
        *(float4*)&Ws[wk][wn] = wv;
        __syncthreads();
        #pragma unroll
        for (int k = 0; k < GBK; ++k) {
            float4 a4 = *(const float4*)&As[k][tm];
            float4 b4 = *(const float4*)&Ws[k][tn];
            float aa[4] = {a4.x, a4.y, a4.z, a4.w};
            float bb[4] = {b4.x, b4.y, b4.z, b4.w};
            #pragma unroll
            for (int i = 0; i < 4; i++)
                #pragma unroll
                for (int j = 0; j < 4; j++)
                    acc[i][j] += aa[i] * bb[j];
        }
    }
    int col = blockIdx.y * GBN + tn;
    #pragma unroll
    for (int i = 0; i < 4; i++) {
        int r = blockIdx.x * GBM + tm + i;
        if (r < M) {
            float4 o = make_float4(acc[i][0], acc[i][1], acc[i][2], acc[i][3]);
            *(float4*)&C[(size_t)r * NC + col] = o;
        }
    }
}

// ---------- CSR gather-aggregation: out[i] = sum_e w_e*h[src_e] + h[i]/deg_i + bias ----------
__global__ __launch_bounds__(256)
void k_agg(const float* __restrict__ hin, float* __restrict__ hout,
           const int* __restrict__ row_ptr, const int* __restrict__ csr_src,
           const float* __restrict__ csr_w, const float* __restrict__ dinv,
           const float* __restrict__ bias, int H) {
    int i = blockIdx.x;
    int t = threadIdx.x;
    float di = dinv[i];
    float acc = hin[(size_t)i * H + t] * (di * di);   // self-loop: dinv_i^2 = 1/deg_i
    int e0 = row_ptr[i], e1 = row_ptr[i + 1];
    for (int e = e0; e < e1; ++e) {
        int   s = csr_src[e];
        float w = csr_w[e];
        acc += w * hin[(size_t)s * H + t];
    }
    hout[(size_t)i * H + t] = acc + bias[t];
}

// ---------- head: BN2 affine + [256x5] dense + sigmoid, one wave per node ----------
__global__ __launch_bounds__(64)
void k_head(const float* __restrict__ h, const float* __restrict__ a, const float* __restrict__ b,
            const float* __restrict__ Wd, const float* __restrict__ bd,
            float* __restrict__ out, int N) {
    int node = blockIdx.x;
    int lane = threadIdx.x;
    int f = lane * 4;
    float4 hv = *(const float4*)(h + (size_t)node * 256 + f);
    float v0 = hv.x * a[f + 0] + b[f + 0];
    float v1 = hv.y * a[f + 1] + b[f + 1];
    float v2 = hv.z * a[f + 2] + b[f + 2];
    float v3 = hv.w * a[f + 3] + b[f + 3];
    float s[5];
    #pragma unroll
    for (int j = 0; j < 5; ++j) {
        s[j] = v0 * Wd[(f + 0) * 5 + j] + v1 * Wd[(f + 1) * 5 + j] +
               v2 * Wd[(f + 2) * 5 + j] + v3 * Wd[(f + 3) * 5 + j];
    }
    #pragma unroll
    for (int off = 32; off > 0; off >>= 1) {
        #pragma unroll
        for (int j = 0; j < 5; ++j) s[j] += __shfl_down(s[j], off);
    }
    if (lane == 0) {
        #pragma unroll
        for (int j = 0; j < 5; ++j) {
            float z = s[j] + bd[j];
            out[(size_t)node * 5 + j] = 1.f / (1.f + expf(-z));
        }
    }
}

extern "C" void kernel_launch(void* const* d_in, const int* in_sizes, int n_in,
                              void* d_out, int out_size, void* d_ws, size_t ws_size,
                              hipStream_t stream) {
    const float* x      = (const float*)d_in[0];
    const void*  ei_raw = d_in[1];
    const float* gamma1 = (const float*)d_in[2];
    const float* beta1  = (const float*)d_in[3];
    const float* W1 = (const float*)d_in[4];
    const float* b1 = (const float*)d_in[5];
    const float* W2 = (const float*)d_in[6];
    const float* b2 = (const float*)d_in[7];
    const float* W3 = (const float*)d_in[8];
    const float* b3 = (const float*)d_in[9];
    const float* W4 = (const float*)d_in[10];
    const float* b4 = (const float*)d_in[11];
    const float* gamma2 = (const float*)d_in[12];
    const float* beta2  = (const float*)d_in[13];
    const float* Wd = (const float*)d_in[14];
    const float* bd = (const float*)d_in[15];

    const int F = in_sizes[2];        // 512
    const int N = in_sizes[0] / F;    // 50000
    const int E = in_sizes[1] / 2;    // 800000
    const int H = in_sizes[5];        // 256
    float* out = (float*)d_out;

    char* p = (char*)d_ws;
    auto alloc = [&](size_t bytes) {
        void* r = (void*)p;
        p += (bytes + 255) & ~(size_t)255;
        return r;
    };
    int*   flag    = (int*)  alloc(4);
    int*   srcA    = (int*)  alloc((size_t)E * 4);
    int*   dstA    = (int*)  alloc((size_t)E * 4);
    int*   cnt     = (int*)  alloc((size_t)N * 4);
    int*   row_ptr = (int*)  alloc(((size_t)N + 1) * 4);
    int*   cursor  = (int*)  alloc((size_t)N * 4);
    float* dinv    = (float*)alloc((size_t)N * 4);
    int*   csr_src = (int*)  alloc((size_t)E * 4);
    float* csr_w   = (float*)alloc((size_t)E * 4);
    float* colsum  = (float*)alloc((size_t)F * 4);
    float* colsq   = (float*)alloc((size_t)F * 4);
    float* bna     = (float*)alloc((size_t)F * 4);
    float* bnb     = (float*)alloc((size_t)F * 4);
    float* hb0     = (float*)alloc((size_t)N * H * 4);
    float* hb1     = (float*)alloc((size_t)N * H * 4);

    hipMemsetAsync(cnt,    0, (size_t)N * 4, stream);
    hipMemsetAsync(colsum, 0, (size_t)F * 4, stream);
    hipMemsetAsync(colsq,  0, (size_t)F * 4, stream);

    int n_check = (E >= 2048) ? 2048 : E;
    k_detect<<<1, 256, 0, stream>>>((const unsigned int*)ei_raw, n_check, flag);
    k_convert<<<(E + 255) / 256, 256, 0, stream>>>(ei_raw, flag, srcA, dstA, E);
    k_count<<<(E + 255) / 256, 256, 0, stream>>>(dstA, cnt, E);
    k_scan<<<1, 1024, 0, stream>>>(cnt, row_ptr, cursor, dinv, N);
    k_fill<<<(E + 255) / 256, 256, 0, stream>>>(srcA, dstA, cursor, dinv, csr_src, csr_w, E);

    const int chunks = 128;
    int rpc = (N + chunks - 1) / chunks;
    k_bnstats<<<dim3((F + 255) / 256, chunks), 256, 0, stream>>>(x, colsum, colsq, N, F, rpc);
    k_bnfin<<<(F + 255) / 256, 256, 0, stream>>>(colsum, colsq, gamma1, beta1, bna, bnb, N, F);

    dim3 gg((N + GBM - 1) / GBM, H / GBN);
    // conv1 (BN1 fused into A-load)
    k_gemm<<<gg, 256, 0, stream>>>(x, W1, hb0, N, F, H, bna, bnb);
    k_agg<<<N, H, 0, stream>>>(hb0, hb1, row_ptr, csr_src, csr_w, dinv, b1, H);
    // conv2
    k_gemm<<<gg, 256, 0, stream>>>(hb1, W2, hb0, N, H, H, nullptr, nullptr);
    k_agg<<<N, H, 0, stream>>>(hb0, hb1, row_ptr, csr_src, csr_w, dinv, b2, H);
    // conv3
    k_gemm<<<gg, 256, 0, stream>>>(hb1, W3, hb0, N, H, H, nullptr, nullptr);
    k_agg<<<N, H, 0, stream>>>(hb0, hb1, row_ptr, csr_src, csr_w, dinv, b3, H);
    // conv4
    k_gemm<<<gg, 256, 0, stream>>>(hb1, W4, hb0, N, H, H, nullptr, nullptr);
    k_agg<<<N, H, 0, stream>>>(hb0, hb1, row_ptr, csr_src, csr_w, dinv, b4, H);

    // BN2 + head
    hipMemsetAsync(colsum, 0, (size_t)H * 4, stream);
    hipMemsetAsync(colsq,  0, (size_t)H * 4, stream);
    k_bnstats<<<dim3((H + 255) / 256, chunks), 256, 0, stream>>>(hb1, colsum, colsq, N, H, rpc);
    k_bnfin<<<(H + 255) / 256, 256, 0, stream>>>(colsum, colsq, gamma2, beta2, bna, bnb, N, H);
    k_head<<<N, 64, 0, stream>>>(hb1, bna, bnb, Wd, bd, out, N);
}

// Round 2
// 1394.570 us; speedup vs baseline: 1.2881x; 1.2881x over previous
//
#include <hip/hip_runtime.h>
#include <math.h>

#define BN_EPS 1e-5f

typedef float floatx4 __attribute__((ext_vector_type(4)));
typedef short shortx8 __attribute__((ext_vector_type(8)));
typedef __bf16 bf16x8 __attribute__((ext_vector_type(8)));

// ---- bf16 helpers (RNE, branch-free; no NaNs in this workload) ----
__device__ __forceinline__ unsigned short f2b(float f) {
    unsigned int u = __builtin_bit_cast(unsigned int, f);
    u += 0x7fffu + ((u >> 16) & 1u);
    return (unsigned short)(u >> 16);
}
__device__ __forceinline__ float b2f(unsigned short s) {
    unsigned int u = ((unsigned int)s) << 16;
    return __builtin_bit_cast(float, u);
}

// ---------- edge-index layout detection (int32 vs int64 storage) ----------
__global__ __launch_bounds__(256)
void k_detect(const unsigned int* __restrict__ ei, int n_check, int* __restrict__ flag) {
    __shared__ int any;
    if (threadIdx.x == 0) any = 0;
    __syncthreads();
    for (int i = threadIdx.x; i < n_check; i += 256) {
        if (ei[2 * i + 1] != 0u) any = 1;
    }
    __syncthreads();
    if (threadIdx.x == 0) *flag = any;   // 1 => int32 layout, 0 => int64 layout
}

__global__ __launch_bounds__(256)
void k_convert(const void* __restrict__ ei_raw, const int* __restrict__ flag,
               int* __restrict__ src, int* __restrict__ dst, int E) {
    int e = blockIdx.x * 256 + threadIdx.x;
    if (e >= E) return;
    if (*flag) {
        const int* a = (const int*)ei_raw;
        src[e] = a[e];
        dst[e] = a[E + e];
    } else {
        const long long* a = (const long long*)ei_raw;
        src[e] = (int)a[e];
        dst[e] = (int)a[E + e];
    }
}

__global__ __launch_bounds__(256)
void k_count(const int* __restrict__ dst, int* __restrict__ cnt, int E) {
    int e = blockIdx.x * 256 + threadIdx.x;
    if (e < E) atomicAdd(&cnt[dst[e]], 1);
}

__global__ __launch_bounds__(1024)
void k_scan(const int* __restrict__ cnt, int* __restrict__ row_ptr, int* __restrict__ cursor,
            float* __restrict__ dinv, int N) {
    __shared__ int sdata[1024];
    __shared__ int carry_s;
    int t = threadIdx.x;
    if (t == 0) carry_s = 0;
    __syncthreads();
    for (int base = 0; base < N; base += 1024) {
        int i = base + t;
        int v = (i < N) ? cnt[i] : 0;
        sdata[t] = v;
        __syncthreads();
        for (int off = 1; off < 1024; off <<= 1) {
            int tmp = (t >= off) ? sdata[t - off] : 0;
            __syncthreads();
            sdata[t] += tmp;
            __syncthreads();
        }
        int incl  = sdata[t];
        int total = sdata[1023];
        int c = carry_s;
        if (i < N) {
            int excl = c + incl - v;
            row_ptr[i] = excl;
            cursor[i]  = excl;
            dinv[i] = rsqrtf((float)(v + 1));
        }
        __syncthreads();
        if (t == 0) carry_s = c + total;
        __syncthreads();
    }
    if (t == 0) row_ptr[N] = carry_s;
}

__global__ __launch_bounds__(256)
void k_fill(const int* __restrict__ src, const int* __restrict__ dst,
            int* __restrict__ cursor, const float* __restrict__ dinv,
            int* __restrict__ csr_src, float* __restrict__ csr_w, int E) {
    int e = blockIdx.x * 256 + threadIdx.x;
    if (e >= E) return;
    int s = src[e], d = dst[e];
    int p = atomicAdd(&cursor[d], 1);
    csr_src[p] = s;
    csr_w[p]   = dinv[s] * dinv[d];
}

// ---------- batchnorm column stats ----------
__global__ __launch_bounds__(256)
void k_bnstats(const float* __restrict__ x, float* __restrict__ sum, float* __restrict__ sumsq,
               int N, int F, int rows_per_chunk) {
    int c = blockIdx.x * 256 + threadIdx.x;
    if (c >= F) return;
    int r0 = blockIdx.y * rows_per_chunk;
    int r1 = min(r0 + rows_per_chunk, N);
    float s = 0.f, ss = 0.f;
    for (int r = r0; r < r1; ++r) {
        float v = x[(size_t)r * F + c];
        s += v; ss += v * v;
    }
    atomicAdd(&sum[c], s);
    atomicAdd(&sumsq[c], ss);
}

__global__ __launch_bounds__(256)
void k_bnfin(const float* __restrict__ sum, const float* __restrict__ sumsq,
             const float* __restrict__ gamma, const float* __restrict__ beta,
             float* __restrict__ a, float* __restrict__ b, int N, int F) {
    int c = blockIdx.x * 256 + threadIdx.x;
    if (c >= F) return;
    float m   = sum[c] / (float)N;
    float var = sumsq[c] / (float)N - m * m;
    float rs  = rsqrtf(var + BN_EPS);
    float aa  = gamma[c] * rs;
    a[c] = aa;
    b[c] = beta[c] - m * aa;
}

// ---------- BN-affine + cast x -> bf16, zero-pad rows [N, Mpad) ----------
__global__ __launch_bounds__(256)
void k_cast_bn(const float* __restrict__ x, const float* __restrict__ a, const float* __restrict__ b,
               unsigned short* __restrict__ xb, int N, int F, int Mpad) {
    int i = blockIdx.x * 256 + threadIdx.x;       // one per 8 elements
    int total = Mpad * (F / 8);
    if (i >= total) return;
    int row = i / (F / 8);
    int col = (i % (F / 8)) * 8;
    shortx8 v;
    if (row < N) {
        #pragma unroll
        for (int j = 0; j < 8; ++j) {
            float f = x[(size_t)row * F + col + j] * a[col + j] + b[col + j];
            v[j] = (short)f2b(f);
        }
    } else {
        #pragma unroll
        for (int j = 0; j < 8; ++j) v[j] = 0;
    }
    *(shortx8*)&xb[(size_t)row * F + col] = v;
}

// ---------- cast + transpose W [K][NC] -> Wt bf16 [NC][K] ----------
__global__ __launch_bounds__(256)
void k_castWT(const float* __restrict__ W, unsigned short* __restrict__ Wt, int K, int NC) {
    int i = blockIdx.x * 256 + threadIdx.x;
    if (i >= K * NC) return;
    int n = i / K, k = i % K;
    Wt[i] = f2b(W[(size_t)k * NC + n]);
}

// ---------- bf16 MFMA GEMM: C[M,NC] = A[M,K] @ Wt[NC,K]^T ----------
// 128x128 block tile, 4 waves in 2x2, each wave 64x64 via 4x4 of 16x16x32 MFMA.
// A, Wt row-major bf16 with K contiguous; M, NC multiples of 128; K multiple of 32.
__device__ __forceinline__ void glds16(const void* g, void* l) {
    __builtin_amdgcn_global_load_lds(
        (const __attribute__((address_space(1))) unsigned int*)g,
        (__attribute__((address_space(3))) unsigned int*)l, 16, 0, 0);
}

__global__ __launch_bounds__(256)
void k_gemm_bf16(const unsigned short* __restrict__ A, const unsigned short* __restrict__ Bt,
                 unsigned short* __restrict__ C, int K, int NC) {
    __shared__ unsigned short As[128 * 32];
    __shared__ unsigned short Bs[128 * 32];
    int tid  = threadIdx.x;
    int wave = tid >> 6, lane = tid & 63;
    int row0 = blockIdx.x * 128;
    int col0 = blockIdx.y * 128;
    int wr = (wave & 1) * 64;
    int wc = (wave >> 1) * 64;

    floatx4 acc[4][4];
    #pragma unroll
    for (int i = 0; i < 4; i++)
        #pragma unroll
        for (int j = 0; j < 4; j++) acc[i][j] = (floatx4){0.f, 0.f, 0.f, 0.f};

    // staging: tile is [128 rows][32 k] bf16 = 8KB = 2 rounds of 256 lanes x 16B
    int cA = tid * 16;                       // byte offset round 0
    int cB = cA + 4096;                      // byte offset round 1
    const char* Ab = (const char*)A;
    const char* Bb = (const char*)Bt;
    size_t a_off0 = (size_t)(row0 + (cA >> 6)) * K * 2 + (cA & 63);
    size_t a_off1 = (size_t)(row0 + (cB >> 6)) * K * 2 + (cB & 63);
    size_t b_off0 = (size_t)(col0 + (cA >> 6)) * K * 2 + (cA & 63);
    size_t b_off1 = (size_t)(col0 + (cB >> 6)) * K * 2 + (cB & 63);

    int lm  = lane & 15;                     // m (or n) within 16
    int lk8 = (lane >> 4) * 8;               // k-group start (elements)

    for (int ks = 0; ks < K; ks += 32) {
        size_t koff = (size_t)ks * 2;
        glds16(Ab + a_off0 + koff, (char*)As + cA);
        glds16(Ab + a_off1 + koff, (char*)As + cA + 4096);
        glds16(Bb + b_off0 + koff, (char*)Bs + cA);
        glds16(Bb + b_off1 + koff, (char*)Bs + cA + 4096);
        __syncthreads();

        bf16x8 af[4], bfr[4];
        #pragma unroll
        for (int i = 0; i < 4; i++) {
            shortx8 s = *(const shortx8*)&As[(wr + i * 16 + lm) * 32 + lk8];
            af[i] = __builtin_bit_cast(bf16x8, s);
        }
        #pragma unroll
        for (int j = 0; j < 4; j++) {
            shortx8 s = *(const shortx8*)&Bs[(wc + j * 16 + lm) * 32 + lk8];
            bfr[j] = __builtin_bit_cast(bf16x8, s);
        }
        #pragma unroll
        for (int i = 0; i < 4; i++)
            #pragma unroll
            for (int j = 0; j < 4; j++)
                acc[i][j] = __builtin_amdgcn_mfma_f32_16x16x32_bf16(af[i], bfr[j], acc[i][j], 0, 0, 0);
        __syncthreads();
    }

    // C/D layout: col = lane&15, row = (lane>>4)*4 + reg
    int crow = row0 + wr + (lane >> 4) * 4;
    int ccol = col0 + wc + lm;
    #pragma unroll
    for (int i = 0; i < 4; i++)
        #pragma unroll
        for (int j = 0; j < 4; j++)
            #pragma unroll
            for (int r = 0; r < 4; r++)
                C[(size_t)(crow + i * 16 + r) * NC + ccol + j * 16] = f2b(acc[i][j][r]);
}

// ---------- CSR gather-aggregation on bf16, fp32 accumulate ----------
__global__ __launch_bounds__(256)
void k_agg(const unsigned short* __restrict__ hin, unsigned short* __restrict__ hout_b,
           float* __restrict__ hout_f,
           const int* __restrict__ row_ptr, const int* __restrict__ csr_src,
           const float* __restrict__ csr_w, const float* __restrict__ dinv,
           const float* __restrict__ bias, int H) {
    int i = blockIdx.x;
    int t = threadIdx.x;
    float di = dinv[i];
    float acc = b2f(hin[(size_t)i * H + t]) * (di * di);
    int e0 = row_ptr[i], e1 = row_ptr[i + 1];
    for (int e = e0; e < e1; ++e) {
        int   s = csr_src[e];
        float w = csr_w[e];
        acc += w * b2f(hin[(size_t)s * H + t]);
    }
    acc += bias[t];
    hout_b[(size_t)i * H + t] = f2b(acc);
    if (hout_f) hout_f[(size_t)i * H + t] = acc;
}

// ---------- head: BN2 affine + [256x5] dense + sigmoid, one wave per node ----------
__global__ __launch_bounds__(64)
void k_head(const float* __restrict__ h, const float* __restrict__ a, const float* __restrict__ b,
            const float* __restrict__ Wd, const float* __restrict__ bd,
            float* __restrict__ out, int N) {
    int node = blockIdx.x;
    int lane = threadIdx.x;
    int f = lane * 4;
    float4 hv = *(const float4*)(h + (size_t)node * 256 + f);
    float v0 = hv.x * a[f + 0] + b[f + 0];
    float v1 = hv.y * a[f + 1] + b[f + 1];
    float v2 = hv.z * a[f + 2] + b[f + 2];
    float v3 = hv.w * a[f + 3] + b[f + 3];
    float s[5];
    #pragma unroll
    for (int j = 0; j < 5; ++j) {
        s[j] = v0 * Wd[(f + 0) * 5 + j] + v1 * Wd[(f + 1) * 5 + j] +
               v2 * Wd[(f + 2) * 5 + j] + v3 * Wd[(f + 3) * 5 + j];
    }
    #pragma unroll
    for (int off = 32; off > 0; off >>= 1) {
        #pragma unroll
        for (int j = 0; j < 5; ++j) s[j] += __shfl_down(s[j], off);
    }
    if (lane == 0) {
        #pragma unroll
        for (int j = 0; j < 5; ++j) {
            float z = s[j] + bd[j];
            out[(size_t)node * 5 + j] = 1.f / (1.f + expf(-z));
        }
    }
}

extern "C" void kernel_launch(void* const* d_in, const int* in_sizes, int n_in,
                              void* d_out, int out_size, void* d_ws, size_t ws_size,
                              hipStream_t stream) {
    const float* x      = (const float*)d_in[0];
    const void*  ei_raw = d_in[1];
    const float* gamma1 = (const float*)d_in[2];
    const float* beta1  = (const float*)d_in[3];
    const float* W1 = (const float*)d_in[4];
    const float* b1 = (const float*)d_in[5];
    const float* W2 = (const float*)d_in[6];
    const float* b2 = (const float*)d_in[7];
    const float* W3 = (const float*)d_in[8];
    const float* b3 = (const float*)d_in[9];
    const float* W4 = (const float*)d_in[10];
    const float* b4 = (const float*)d_in[11];
    const float* gamma2 = (const float*)d_in[12];
    const float* beta2  = (const float*)d_in[13];
    const float* Wd = (const float*)d_in[14];
    const float* bd = (const float*)d_in[15];

    const int F = in_sizes[2];        // 512
    const int N = in_sizes[0] / F;    // 50000
    const int E = in_sizes[1] / 2;    // 800000
    const int H = in_sizes[5];        // 256
    const int Mpad = ((N + 127) / 128) * 128;   // 50048
    float* out = (float*)d_out;

    char* p = (char*)d_ws;
    auto alloc = [&](size_t bytes) {
        void* r = (void*)p;
        p += (bytes + 255) & ~(size_t)255;
        return r;
    };
    int*   flag    = (int*)  alloc(4);
    int*   srcA    = (int*)  alloc((size_t)E * 4);
    int*   dstA    = (int*)  alloc((size_t)E * 4);
    int*   cnt     = (int*)  alloc((size_t)N * 4);
    int*   row_ptr = (int*)  alloc(((size_t)N + 1) * 4);
    int*   cursor  = (int*)  alloc((size_t)N * 4);
    float* dinv    = (float*)alloc((size_t)N * 4);
    int*   csr_src = (int*)  alloc((size_t)E * 4);
    float* csr_w   = (float*)alloc((size_t)E * 4);
    float* colsum  = (float*)alloc((size_t)F * 4);
    float* colsq   = (float*)alloc((size_t)F * 4);
    float* bna     = (float*)alloc((size_t)F * 4);
    float* bnb     = (float*)alloc((size_t)F * 4);
    unsigned short* W1t = (unsigned short*)alloc((size_t)F * H * 2);
    unsigned short* W2t = (unsigned short*)alloc((size_t)H * H * 2);
    unsigned short* W3t = (unsigned short*)alloc((size_t)H * H * 2);
    unsigned short* W4t = (unsigned short*)alloc((size_t)H * H * 2);
    // xb (bf16 [Mpad][F]) aliases hbF (fp32 [Mpad][H]) — disjoint lifetimes
    unsigned short* xb  = (unsigned short*)alloc((size_t)Mpad * F * 2);
    float* hbF          = (float*)xb;
    unsigned short* hbA = (unsigned short*)alloc((size_t)Mpad * H * 2);
    unsigned short* hbB = (unsigned short*)alloc((size_t)Mpad * H * 2);

    hipMemsetAsync(cnt,    0, (size_t)N * 4, stream);
    hipMemsetAsync(colsum, 0, (size_t)F * 4, stream);
    hipMemsetAsync(colsq,  0, (size_t)F * 4, stream);

    // graph build
    int n_check = (E >= 2048) ? 2048 : E;
    k_detect<<<1, 256, 0, stream>>>((const unsigned int*)ei_raw, n_check, flag);
    k_convert<<<(E + 255) / 256, 256, 0, stream>>>(ei_raw, flag, srcA, dstA, E);
    k_count<<<(E + 255) / 256, 256, 0, stream>>>(dstA, cnt, E);
    k_scan<<<1, 1024, 0, stream>>>(cnt, row_ptr, cursor, dinv, N);
    k_fill<<<(E + 255) / 256, 256, 0, stream>>>(srcA, dstA, cursor, dinv, csr_src, csr_w, E);

    // BN1 + cast
    const int chunks = 128;
    int rpc = (N + chunks - 1) / chunks;
    k_bnstats<<<dim3((F + 255) / 256, chunks), 256, 0, stream>>>(x, colsum, colsq, N, F, rpc);
    k_bnfin<<<(F + 255) / 256, 256, 0, stream>>>(colsum, colsq, gamma1, beta1, bna, bnb, N, F);
    k_cast_bn<<<(Mpad * (F / 8) + 255) / 256, 256, 0, stream>>>(x, bna, bnb, xb, N, F, Mpad);

    // weight casts (+transpose)
    k_castWT<<<(F * H + 255) / 256, 256, 0, stream>>>(W1, W1t, F, H);
    k_castWT<<<(H * H + 255) / 256, 256, 0, stream>>>(W2, W2t, H, H);
    k_castWT<<<(H * H + 255) / 256, 256, 0, stream>>>(W3, W3t, H, H);
    k_castWT<<<(H * H + 255) / 256, 256, 0, stream>>>(W4, W4t, H, H);

    dim3 gg(Mpad / 128, H / 128);
    // conv1
    k_gemm_bf16<<<gg, 256, 0, stream>>>(xb, W1t, hbA, F, H);
    k_agg<<<N, H, 0, stream>>>(hbA, hbB, nullptr, row_ptr, csr_src, csr_w, dinv, b1, H);
    // conv2
    k_gemm_bf16<<<gg, 256, 0, stream>>>(hbB, W2t, hbA, H, H);
    k_agg<<<N, H, 0, stream>>>(hbA, hbB, nullptr, row_ptr, csr_src, csr_w, dinv, b2, H);
    // conv3
    k_gemm_bf16<<<gg, 256, 0, stream>>>(hbB, W3t, hbA, H, H);
    k_agg<<<N, H, 0, stream>>>(hbA, hbB, nullptr, row_ptr, csr_src, csr_w, dinv, b3, H);
    // conv4 (agg also emits fp32 for BN2/head; hbF aliases xb, last read at conv1)
    k_gemm_bf16<<<gg, 256, 0, stream>>>(hbB, W4t, hbA, H, H);
    k_agg<<<N, H, 0, stream>>>(hbA, hbB, hbF, row_ptr, csr_src, csr_w, dinv, b4, H);

    // BN2 + head
    hipMemsetAsync(colsum, 0, (size_t)H * 4, stream);
    hipMemsetAsync(colsq,  0, (size_t)H * 4, stream);
    k_bnstats<<<dim3((H + 255) / 256, chunks), 256, 0, stream>>>(hbF, colsum, colsq, N, H, rpc);
    k_bnfin<<<(H + 255) / 256, 256, 0, stream>>>(colsum, colsq, gamma2, beta2, bna, bnb, N, H);
    k_head<<<N, 64, 0, stream>>>(hbF, bna, bnb, Wd, bd, out, N);
}

// Round 3
// 719.008 us; speedup vs baseline: 2.4983x; 1.9396x over previous
//
#include <hip/hip_runtime.h>
#include <math.h>

#define BN_EPS 1e-5f

typedef float floatx4 __attribute__((ext_vector_type(4)));
typedef short shortx4 __attribute__((ext_vector_type(4)));
typedef short shortx8 __attribute__((ext_vector_type(8)));
typedef __bf16 bf16x8 __attribute__((ext_vector_type(8)));

// ---- bf16 helpers (RNE, branch-free; no NaNs in this workload) ----
__device__ __forceinline__ unsigned short f2b(float f) {
    unsigned int u = __builtin_bit_cast(unsigned int, f);
    u += 0x7fffu + ((u >> 16) & 1u);
    return (unsigned short)(u >> 16);
}
__device__ __forceinline__ float b2f(unsigned short s) {
    unsigned int u = ((unsigned int)s) << 16;
    return __builtin_bit_cast(float, u);
}
__device__ __forceinline__ float b2f_s(short s) { return b2f((unsigned short)s); }

// ---------- edge-index layout detection (int32 vs int64 storage) ----------
__global__ __launch_bounds__(256)
void k_detect(const unsigned int* __restrict__ ei, int n_check, int* __restrict__ flag) {
    __shared__ int any;
    if (threadIdx.x == 0) any = 0;
    __syncthreads();
    for (int i = threadIdx.x; i < n_check; i += 256) {
        if (ei[2 * i + 1] != 0u) any = 1;
    }
    __syncthreads();
    if (threadIdx.x == 0) *flag = any;   // 1 => int32 layout, 0 => int64 layout
}

__global__ __launch_bounds__(256)
void k_convert(const void* __restrict__ ei_raw, const int* __restrict__ flag,
               int* __restrict__ src, int* __restrict__ dst, int E) {
    int e = blockIdx.x * 256 + threadIdx.x;
    if (e >= E) return;
    if (*flag) {
        const int* a = (const int*)ei_raw;
        src[e] = a[e];
        dst[e] = a[E + e];
    } else {
        const long long* a = (const long long*)ei_raw;
        src[e] = (int)a[e];
        dst[e] = (int)a[E + e];
    }
}

__global__ __launch_bounds__(256)
void k_count(const int* __restrict__ dst, int* __restrict__ cnt, int E) {
    int e = blockIdx.x * 256 + threadIdx.x;
    if (e < E) atomicAdd(&cnt[dst[e]], 1);
}

// ---------- 3-phase parallel exclusive scan ----------
__global__ __launch_bounds__(1024)
void k_scan_sum(const int* __restrict__ cnt, int* __restrict__ bsum, int N) {
    __shared__ int s[1024];
    int i = blockIdx.x * 1024 + threadIdx.x;
    s[threadIdx.x] = (i < N) ? cnt[i] : 0;
    __syncthreads();
    for (int off = 512; off > 0; off >>= 1) {
        if (threadIdx.x < off) s[threadIdx.x] += s[threadIdx.x + off];
        __syncthreads();
    }
    if (threadIdx.x == 0) bsum[blockIdx.x] = s[0];
}

__global__ __launch_bounds__(1024)
void k_scan_part(int* __restrict__ bsum, int nb) {
    __shared__ int s[1024];
    int t = threadIdx.x;
    int v = (t < nb) ? bsum[t] : 0;
    s[t] = v;
    __syncthreads();
    for (int off = 1; off < 1024; off <<= 1) {
        int tmp = (t >= off) ? s[t - off] : 0;
        __syncthreads();
        s[t] += tmp;
        __syncthreads();
    }
    if (t < nb) bsum[t] = s[t] - v;     // exclusive
}

__global__ __launch_bounds__(1024)
void k_scan_final(const int* __restrict__ cnt, const int* __restrict__ bsum,
                  int* __restrict__ row_ptr, int* __restrict__ cursor,
                  float* __restrict__ dinv, int N) {
    __shared__ int s[1024];
    int b = blockIdx.x, t = threadIdx.x;
    int i = b * 1024 + t;
    int v = (i < N) ? cnt[i] : 0;
    s[t] = v;
    __syncthreads();
    for (int off = 1; off < 1024; off <<= 1) {
        int tmp = (t >= off) ? s[t - off] : 0;
        __syncthreads();
        s[t] += tmp;
        __syncthreads();
    }
    if (i < N) {
        int excl = bsum[b] + s[t] - v;
        row_ptr[i] = excl;
        cursor[i]  = excl;
        dinv[i] = rsqrtf((float)(v + 1));
        if (i == N - 1) row_ptr[N] = excl + v;
    }
}

__global__ __launch_bounds__(256)
void k_fill(const int* __restrict__ src, const int* __restrict__ dst,
            int* __restrict__ cursor, const float* __restrict__ dinv,
            int* __restrict__ csr_src, float* __restrict__ csr_w, int E) {
    int e = blockIdx.x * 256 + threadIdx.x;
    if (e >= E) return;
    int s = src[e], d = dst[e];
    int p = atomicAdd(&cursor[d], 1);
    csr_src[p] = s;
    csr_w[p]   = dinv[s] * dinv[d];
}

// ---------- batchnorm column stats: grid-stride float4 rows, LDS reduce ----------
__global__ __launch_bounds__(256)
void k_bnstats(const float* __restrict__ x, float* __restrict__ sum, float* __restrict__ sumsq,
               int N, int F) {
    __shared__ float ls[512], lq[512];
    int q   = F >> 2;            // column quads per row (128 for F=512, 64 for F=256)
    int t   = threadIdx.x;
    int cq  = t % q;             // this thread's column quad
    int ro  = t / q;             // row offset within block pass
    int rpp = 256 / q;           // rows per block pass
    float s0 = 0.f, s1 = 0.f, s2 = 0.f, s3 = 0.f;
    float q0 = 0.f, q1 = 0.f, q2 = 0.f, q3 = 0.f;
    for (int r = blockIdx.x * rpp + ro; r < N; r += gridDim.x * rpp) {
        float4 v = *(const float4*)&x[(size_t)r * F + cq * 4];
        s0 += v.x; s1 += v.y; s2 += v.z; s3 += v.w;
        q0 += v.x * v.x; q1 += v.y * v.y; q2 += v.z * v.z; q3 += v.w * v.w;
    }
    for (int c = t; c < F; c += 256) { ls[c] = 0.f; lq[c] = 0.f; }
    __syncthreads();
    atomicAdd(&ls[cq * 4 + 0], s0); atomicAdd(&ls[cq * 4 + 1], s1);
    atomicAdd(&ls[cq * 4 + 2], s2); atomicAdd(&ls[cq * 4 + 3], s3);
    atomicAdd(&lq[cq * 4 + 0], q0); atomicAdd(&lq[cq * 4 + 1], q1);
    atomicAdd(&lq[cq * 4 + 2], q2); atomicAdd(&lq[cq * 4 + 3], q3);
    __syncthreads();
    for (int c = t; c < F; c += 256) {
        atomicAdd(&sum[c],   ls[c]);
        atomicAdd(&sumsq[c], lq[c]);
    }
}

__global__ __launch_bounds__(256)
void k_bnfin(const float* __restrict__ sum, const float* __restrict__ sumsq,
             const float* __restrict__ gamma, const float* __restrict__ beta,
             float* __restrict__ a, float* __restrict__ b, int N, int F) {
    int c = blockIdx.x * 256 + threadIdx.x;
    if (c >= F) return;
    float m   = sum[c] / (float)N;
    float var = sumsq[c] / (float)N - m * m;
    float rs  = rsqrtf(var + BN_EPS);
    float aa  = gamma[c] * rs;
    a[c] = aa;
    b[c] = beta[c] - m * aa;
}

// ---------- BN-affine + cast x -> bf16, zero-pad rows [N, Mpad) ----------
__global__ __launch_bounds__(256)
void k_cast_bn(const float* __restrict__ x, const float* __restrict__ a, const float* __restrict__ b,
               unsigned short* __restrict__ xb, int N, int F, int Mpad) {
    int i = blockIdx.x * 256 + threadIdx.x;       // one per 8 elements
    int total = Mpad * (F / 8);
    if (i >= total) return;
    int row = i / (F / 8);
    int col = (i % (F / 8)) * 8;
    shortx8 v;
    if (row < N) {
        float4 x0 = *(const float4*)&x[(size_t)row * F + col];
        float4 x1 = *(const float4*)&x[(size_t)row * F + col + 4];
        float4 a0 = *(const float4*)&a[col];
        float4 a1 = *(const float4*)&a[col + 4];
        float4 b0 = *(const float4*)&b[col];
        float4 b1 = *(const float4*)&b[col + 4];
        v[0] = (short)f2b(x0.x * a0.x + b0.x);
        v[1] = (short)f2b(x0.y * a0.y + b0.y);
        v[2] = (short)f2b(x0.z * a0.z + b0.z);
        v[3] = (short)f2b(x0.w * a0.w + b0.w);
        v[4] = (short)f2b(x1.x * a1.x + b1.x);
        v[5] = (short)f2b(x1.y * a1.y + b1.y);
        v[6] = (short)f2b(x1.z * a1.z + b1.z);
        v[7] = (short)f2b(x1.w * a1.w + b1.w);
    } else {
        #pragma unroll
        for (int j = 0; j < 8; ++j) v[j] = 0;
    }
    *(shortx8*)&xb[(size_t)row * F + col] = v;
}

// ---------- cast + transpose W [K][NC] -> Wt bf16 [NC][K] ----------
__global__ __launch_bounds__(256)
void k_castWT(const float* __restrict__ W, unsigned short* __restrict__ Wt, int K, int NC) {
    int i = blockIdx.x * 256 + threadIdx.x;
    if (i >= K * NC) return;
    int n = i / K, k = i % K;
    Wt[i] = f2b(W[(size_t)k * NC + n]);
}

// ---------- bf16 MFMA GEMM: C[M,NC] = A[M,K] @ Wt[NC,K]^T ----------
__device__ __forceinline__ void glds16(const void* g, void* l) {
    __builtin_amdgcn_global_load_lds(
        (const __attribute__((address_space(1))) unsigned int*)g,
        (__attribute__((address_space(3))) unsigned int*)l, 16, 0, 0);
}

__global__ __launch_bounds__(256)
void k_gemm_bf16(const unsigned short* __restrict__ A, const unsigned short* __restrict__ Bt,
                 unsigned short* __restrict__ C, int K, int NC) {
    __shared__ unsigned short As[128 * 32];
    __shared__ unsigned short Bs[128 * 32];
    int tid  = threadIdx.x;
    int wave = tid >> 6, lane = tid & 63;
    int row0 = blockIdx.x * 128;
    int col0 = blockIdx.y * 128;
    int wr = (wave & 1) * 64;
    int wc = (wave >> 1) * 64;

    floatx4 acc[4][4];
    #pragma unroll
    for (int i = 0; i < 4; i++)
        #pragma unroll
        for (int j = 0; j < 4; j++) acc[i][j] = (floatx4){0.f, 0.f, 0.f, 0.f};

    int cA = tid * 16;
    int cB = cA + 4096;
    const char* Ab = (const char*)A;
    const char* Bb = (const char*)Bt;
    size_t a_off0 = (size_t)(row0 + (cA >> 6)) * K * 2 + (cA & 63);
    size_t a_off1 = (size_t)(row0 + (cB >> 6)) * K * 2 + (cB & 63);
    size_t b_off0 = (size_t)(col0 + (cA >> 6)) * K * 2 + (cA & 63);
    size_t b_off1 = (size_t)(col0 + (cB >> 6)) * K * 2 + (cB & 63);

    int lm  = lane & 15;
    int lk8 = (lane >> 4) * 8;

    for (int ks = 0; ks < K; ks += 32) {
        size_t koff = (size_t)ks * 2;
        glds16(Ab + a_off0 + koff, (char*)As + cA);
        glds16(Ab + a_off1 + koff, (char*)As + cA + 4096);
        glds16(Bb + b_off0 + koff, (char*)Bs + cA);
        glds16(Bb + b_off1 + koff, (char*)Bs + cA + 4096);
        __syncthreads();

        bf16x8 af[4], bfr[4];
        #pragma unroll
        for (int i = 0; i < 4; i++) {
            shortx8 s = *(const shortx8*)&As[(wr + i * 16 + lm) * 32 + lk8];
            af[i] = __builtin_bit_cast(bf16x8, s);
        }
        #pragma unroll
        for (int j = 0; j < 4; j++) {
            shortx8 s = *(const shortx8*)&Bs[(wc + j * 16 + lm) * 32 + lk8];
            bfr[j] = __builtin_bit_cast(bf16x8, s);
        }
        #pragma unroll
        for (int i = 0; i < 4; i++)
            #pragma unroll
            for (int j = 0; j < 4; j++)
                acc[i][j] = __builtin_amdgcn_mfma_f32_16x16x32_bf16(af[i], bfr[j], acc[i][j], 0, 0, 0);
        __syncthreads();
    }

    int crow = row0 + wr + (lane >> 4) * 4;
    int ccol = col0 + wc + lm;
    #pragma unroll
    for (int i = 0; i < 4; i++)
        #pragma unroll
        for (int j = 0; j < 4; j++)
            #pragma unroll
            for (int r = 0; r < 4; r++)
                C[(size_t)(crow + i * 16 + r) * NC + ccol + j * 16] = f2b(acc[i][j][r]);
}

// ---------- CSR gather-aggregation: wave per node, lane owns 4 features, 4x unrolled ----------
__global__ __launch_bounds__(256)
void k_agg(const unsigned short* __restrict__ hin, unsigned short* __restrict__ hout_b,
           float* __restrict__ hout_f,
           const int* __restrict__ row_ptr, const int* __restrict__ csr_src,
           const float* __restrict__ csr_w, const float* __restrict__ dinv,
           const float* __restrict__ bias, int N) {
    const int H = 256;
    int node = blockIdx.x * 4 + (threadIdx.x >> 6);
    if (node >= N) return;
    int lane = threadIdx.x & 63;
    int f = lane * 4;
    float di = dinv[node];
    float sl = di * di;
    shortx4 hv = *(const shortx4*)&hin[(size_t)node * H + f];
    float a0 = b2f_s(hv[0]) * sl, a1 = b2f_s(hv[1]) * sl;
    float a2 = b2f_s(hv[2]) * sl, a3 = b2f_s(hv[3]) * sl;
    int e0 = row_ptr[node], e1 = row_ptr[node + 1];
    int e = e0;
    for (; e + 4 <= e1; e += 4) {
        int   s0 = csr_src[e],     s1 = csr_src[e + 1];
        int   s2 = csr_src[e + 2], s3 = csr_src[e + 3];
        float w0 = csr_w[e],     w1 = csr_w[e + 1];
        float w2 = csr_w[e + 2], w3 = csr_w[e + 3];
        shortx4 r0 = *(const shortx4*)&hin[(size_t)s0 * H + f];
        shortx4 r1 = *(const shortx4*)&hin[(size_t)s1 * H + f];
        shortx4 r2 = *(const shortx4*)&hin[(size_t)s2 * H + f];
        shortx4 r3 = *(const shortx4*)&hin[(size_t)s3 * H + f];
        a0 += w0 * b2f_s(r0[0]) + w1 * b2f_s(r1[0]) + w2 * b2f_s(r2[0]) + w3 * b2f_s(r3[0]);
        a1 += w0 * b2f_s(r0[1]) + w1 * b2f_s(r1[1]) + w2 * b2f_s(r2[1]) + w3 * b2f_s(r3[1]);
        a2 += w0 * b2f_s(r0[2]) + w1 * b2f_s(r1[2]) + w2 * b2f_s(r2[2]) + w3 * b2f_s(r3[2]);
        a3 += w0 * b2f_s(r0[3]) + w1 * b2f_s(r1[3]) + w2 * b2f_s(r2[3]) + w3 * b2f_s(r3[3]);
    }
    for (; e < e1; ++e) {
        int   s = csr_src[e];
        float w = csr_w[e];
        shortx4 r = *(const shortx4*)&hin[(size_t)s * H + f];
        a0 += w * b2f_s(r[0]); a1 += w * b2f_s(r[1]);
        a2 += w * b2f_s(r[2]); a3 += w * b2f_s(r[3]);
    }
    float4 bi = *(const float4*)&bias[f];
    a0 += bi.x; a1 += bi.y; a2 += bi.z; a3 += bi.w;
    shortx4 o;
    o[0] = (short)f2b(a0); o[1] = (short)f2b(a1);
    o[2] = (short)f2b(a2); o[3] = (short)f2b(a3);
    *(shortx4*)&hout_b[(size_t)node * H + f] = o;
    if (hout_f) {
        float4 of = make_float4(a0, a1, a2, a3);
        *(float4*)&hout_f[(size_t)node * H + f] = of;
    }
}

// ---------- head: BN2 affine + [256x5] dense + sigmoid, one wave per node ----------
__global__ __launch_bounds__(64)
void k_head(const float* __restrict__ h, const float* __restrict__ a, const float* __restrict__ b,
            const float* __restrict__ Wd, const float* __restrict__ bd,
            float* __restrict__ out, int N) {
    int node = blockIdx.x;
    int lane = threadIdx.x;
    int f = lane * 4;
    float4 hv = *(const float4*)(h + (size_t)node * 256 + f);
    float v0 = hv.x * a[f + 0] + b[f + 0];
    float v1 = hv.y * a[f + 1] + b[f + 1];
    float v2 = hv.z * a[f + 2] + b[f + 2];
    float v3 = hv.w * a[f + 3] + b[f + 3];
    float s[5];
    #pragma unroll
    for (int j = 0; j < 5; ++j) {
        s[j] = v0 * Wd[(f + 0) * 5 + j] + v1 * Wd[(f + 1) * 5 + j] +
               v2 * Wd[(f + 2) * 5 + j] + v3 * Wd[(f + 3) * 5 + j];
    }
    #pragma unroll
    for (int off = 32; off > 0; off >>= 1) {
        #pragma unroll
        for (int j = 0; j < 5; ++j) s[j] += __shfl_down(s[j], off);
    }
    if (lane == 0) {
        #pragma unroll
        for (int j = 0; j < 5; ++j) {
            float z = s[j] + bd[j];
            out[(size_t)node * 5 + j] = 1.f / (1.f + expf(-z));
        }
    }
}

extern "C" void kernel_launch(void* const* d_in, const int* in_sizes, int n_in,
                              void* d_out, int out_size, void* d_ws, size_t ws_size,
                              hipStream_t stream) {
    const float* x      = (const float*)d_in[0];
    const void*  ei_raw = d_in[1];
    const float* gamma1 = (const float*)d_in[2];
    const float* beta1  = (const float*)d_in[3];
    const float* W1 = (const float*)d_in[4];
    const float* b1 = (const float*)d_in[5];
    const float* W2 = (const float*)d_in[6];
    const float* b2 = (const float*)d_in[7];
    const float* W3 = (const float*)d_in[8];
    const float* b3 = (const float*)d_in[9];
    const float* W4 = (const float*)d_in[10];
    const float* b4 = (const float*)d_in[11];
    const float* gamma2 = (const float*)d_in[12];
    const float* beta2  = (const float*)d_in[13];
    const float* Wd = (const float*)d_in[14];
    const float* bd = (const float*)d_in[15];

    const int F = in_sizes[2];        // 512
    const int N = in_sizes[0] / F;    // 50000
    const int E = in_sizes[1] / 2;    // 800000
    const int H = in_sizes[5];        // 256
    const int Mpad = ((N + 127) / 128) * 128;   // 50048
    const int NB   = (N + 1023) / 1024;         // scan blocks
    float* out = (float*)d_out;

    char* p = (char*)d_ws;
    auto alloc = [&](size_t bytes) {
        void* r = (void*)p;
        p += (bytes + 255) & ~(size_t)255;
        return r;
    };
    int*   flag    = (int*)  alloc(4);
    int*   srcA    = (int*)  alloc((size_t)E * 4);
    int*   dstA    = (int*)  alloc((size_t)E * 4);
    int*   cnt     = (int*)  alloc((size_t)N * 4);
    int*   row_ptr = (int*)  alloc(((size_t)N + 1) * 4);
    int*   cursor  = (int*)  alloc((size_t)N * 4);
    float* dinv    = (float*)alloc((size_t)N * 4);
    int*   csr_src = (int*)  alloc((size_t)E * 4);
    float* csr_w   = (float*)alloc((size_t)E * 4);
    int*   bsum    = (int*)  alloc((size_t)NB * 4);
    float* colsum  = (float*)alloc((size_t)F * 4);
    float* colsq   = (float*)alloc((size_t)F * 4);
    float* bna     = (float*)alloc((size_t)F * 4);
    float* bnb     = (float*)alloc((size_t)F * 4);
    unsigned short* W1t = (unsigned short*)alloc((size_t)F * H * 2);
    unsigned short* W2t = (unsigned short*)alloc((size_t)H * H * 2);
    unsigned short* W3t = (unsigned short*)alloc((size_t)H * H * 2);
    unsigned short* W4t = (unsigned short*)alloc((size_t)H * H * 2);
    // xb (bf16 [Mpad][F]) aliases hbF (fp32 [Mpad][H]) — disjoint lifetimes
    unsigned short* xb  = (unsigned short*)alloc((size_t)Mpad * F * 2);
    float* hbF          = (float*)xb;
    unsigned short* hbA = (unsigned short*)alloc((size_t)Mpad * H * 2);
    unsigned short* hbB = (unsigned short*)alloc((size_t)Mpad * H * 2);

    hipMemsetAsync(cnt,    0, (size_t)N * 4, stream);
    hipMemsetAsync(colsum, 0, (size_t)F * 4, stream);
    hipMemsetAsync(colsq,  0, (size_t)F * 4, stream);

    // graph build
    int n_check = (E >= 2048) ? 2048 : E;
    k_detect<<<1, 256, 0, stream>>>((const unsigned int*)ei_raw, n_check, flag);
    k_convert<<<(E + 255) / 256, 256, 0, stream>>>(ei_raw, flag, srcA, dstA, E);
    k_count<<<(E + 255) / 256, 256, 0, stream>>>(dstA, cnt, E);
    k_scan_sum<<<NB, 1024, 0, stream>>>(cnt, bsum, N);
    k_scan_part<<<1, 1024, 0, stream>>>(bsum, NB);
    k_scan_final<<<NB, 1024, 0, stream>>>(cnt, bsum, row_ptr, cursor, dinv, N);
    k_fill<<<(E + 255) / 256, 256, 0, stream>>>(srcA, dstA, cursor, dinv, csr_src, csr_w, E);

    // BN1 + cast
    k_bnstats<<<512, 256, 0, stream>>>(x, colsum, colsq, N, F);
    k_bnfin<<<(F + 255) / 256, 256, 0, stream>>>(colsum, colsq, gamma1, beta1, bna, bnb, N, F);
    k_cast_bn<<<(Mpad * (F / 8) + 255) / 256, 256, 0, stream>>>(x, bna, bnb, xb, N, F, Mpad);

    // weight casts (+transpose)
    k_castWT<<<(F * H + 255) / 256, 256, 0, stream>>>(W1, W1t, F, H);
    k_castWT<<<(H * H + 255) / 256, 256, 0, stream>>>(W2, W2t, H, H);
    k_castWT<<<(H * H + 255) / 256, 256, 0, stream>>>(W3, W3t, H, H);
    k_castWT<<<(H * H + 255) / 256, 256, 0, stream>>>(W4, W4t, H, H);

    dim3 gg(Mpad / 128, H / 128);
    int aggb = (N + 3) / 4;
    // conv1
    k_gemm_bf16<<<gg, 256, 0, stream>>>(xb, W1t, hbA, F, H);
    k_agg<<<aggb, 256, 0, stream>>>(hbA, hbB, nullptr, row_ptr, csr_src, csr_w, dinv, b1, N);
    // conv2
    k_gemm_bf16<<<gg, 256, 0, stream>>>(hbB, W2t, hbA, H, H);
    k_agg<<<aggb, 256, 0, stream>>>(hbA, hbB, nullptr, row_ptr, csr_src, csr_w, dinv, b2, N);
    // conv3
    k_gemm_bf16<<<gg, 256, 0, stream>>>(hbB, W3t, hbA, H, H);
    k_agg<<<aggb, 256, 0, stream>>>(hbA, hbB, nullptr, row_ptr, csr_src, csr_w, dinv, b3, N);
    // conv4 (agg also emits fp32 for BN2/head; hbF aliases xb, last read at conv1)
    k_gemm_bf16<<<gg, 256, 0, stream>>>(hbB, W4t, hbA, H, H);
    k_agg<<<aggb, 256, 0, stream>>>(hbA, hbB, hbF, row_ptr, csr_src, csr_w, dinv, b4, N);

    // BN2 + head
    hipMemsetAsync(colsum, 0, (size_t)H * 4, stream);
    hipMemsetAsync(colsq,  0, (size_t)H * 4, stream);
    k_bnstats<<<512, 256, 0, stream>>>(hbF, colsum, colsq, N, H);
    k_bnfin<<<(H + 255) / 256, 256, 0, stream>>>(colsum, colsq, gamma2, beta2, bna, bnb, N, H);
    k_head<<<N, 64, 0, stream>>>(hbF, bna, bnb, Wd, bd, out, N);
}

// Round 4
// 712.855 us; speedup vs baseline: 2.5199x; 1.0086x over previous
//
#include <hip/hip_runtime.h>
#include <math.h>

#define BN_EPS 1e-5f

typedef float floatx4 __attribute__((ext_vector_type(4)));
typedef short shortx4 __attribute__((ext_vector_type(4)));
typedef short shortx8 __attribute__((ext_vector_type(8)));
typedef __bf16 bf16x8 __attribute__((ext_vector_type(8)));

// ---- bf16 helpers (RNE, branch-free; no NaNs in this workload) ----
__device__ __forceinline__ unsigned short f2b(float f) {
    unsigned int u = __builtin_bit_cast(unsigned int, f);
    u += 0x7fffu + ((u >> 16) & 1u);
    return (unsigned short)(u >> 16);
}
__device__ __forceinline__ float b2f(unsigned short s) {
    unsigned int u = ((unsigned int)s) << 16;
    return __builtin_bit_cast(float, u);
}
__device__ __forceinline__ float b2f_s(short s) { return b2f((unsigned short)s); }

// ---------- edge-index layout detection (int32 vs int64 storage) ----------
__global__ __launch_bounds__(256)
void k_detect(const unsigned int* __restrict__ ei, int n_check, int* __restrict__ flag) {
    __shared__ int any;
    if (threadIdx.x == 0) any = 0;
    __syncthreads();
    for (int i = threadIdx.x; i < n_check; i += 256) {
        if (ei[2 * i + 1] != 0u) any = 1;
    }
    __syncthreads();
    if (threadIdx.x == 0) *flag = any;   // 1 => int32 layout, 0 => int64 layout
}

__global__ __launch_bounds__(256)
void k_convert(const void* __restrict__ ei_raw, const int* __restrict__ flag,
               int* __restrict__ src, int* __restrict__ dst, int E) {
    int e = blockIdx.x * 256 + threadIdx.x;
    if (e >= E) return;
    if (*flag) {
        const int* a = (const int*)ei_raw;
        src[e] = a[e];
        dst[e] = a[E + e];
    } else {
        const long long* a = (const long long*)ei_raw;
        src[e] = (int)a[e];
        dst[e] = (int)a[E + e];
    }
}

__global__ __launch_bounds__(256)
void k_count(const int* __restrict__ dst, int* __restrict__ cnt, int E) {
    int e = blockIdx.x * 256 + threadIdx.x;
    if (e < E) atomicAdd(&cnt[dst[e]], 1);
}

// ---------- 3-phase parallel exclusive scan ----------
__global__ __launch_bounds__(1024)
void k_scan_sum(const int* __restrict__ cnt, int* __restrict__ bsum, int N) {
    __shared__ int s[1024];
    int i = blockIdx.x * 1024 + threadIdx.x;
    s[threadIdx.x] = (i < N) ? cnt[i] : 0;
    __syncthreads();
    for (int off = 512; off > 0; off >>= 1) {
        if (threadIdx.x < off) s[threadIdx.x] += s[threadIdx.x + off];
        __syncthreads();
    }
    if (threadIdx.x == 0) bsum[blockIdx.x] = s[0];
}

__global__ __launch_bounds__(1024)
void k_scan_part(int* __restrict__ bsum, int nb) {
    __shared__ int s[1024];
    int t = threadIdx.x;
    int v = (t < nb) ? bsum[t] : 0;
    s[t] = v;
    __syncthreads();
    for (int off = 1; off < 1024; off <<= 1) {
        int tmp = (t >= off) ? s[t - off] : 0;
        __syncthreads();
        s[t] += tmp;
        __syncthreads();
    }
    if (t < nb) bsum[t] = s[t] - v;     // exclusive
}

__global__ __launch_bounds__(1024)
void k_scan_final(const int* __restrict__ cnt, const int* __restrict__ bsum,
                  int* __restrict__ row_ptr, int* __restrict__ cursor,
                  float* __restrict__ dinv, int N) {
    __shared__ int s[1024];
    int b = blockIdx.x, t = threadIdx.x;
    int i = b * 1024 + t;
    int v = (i < N) ? cnt[i] : 0;
    s[t] = v;
    __syncthreads();
    for (int off = 1; off < 1024; off <<= 1) {
        int tmp = (t >= off) ? s[t - off] : 0;
        __syncthreads();
        s[t] += tmp;
        __syncthreads();
    }
    if (i < N) {
        int excl = bsum[b] + s[t] - v;
        row_ptr[i] = excl;
        cursor[i]  = excl;
        dinv[i] = rsqrtf((float)(v + 1));
        if (i == N - 1) row_ptr[N] = excl + v;
    }
}

// ---------- CSR fill: packed (src, weight) pairs ----------
__global__ __launch_bounds__(256)
void k_fill(const int* __restrict__ src, const int* __restrict__ dst,
            int* __restrict__ cursor, const float* __restrict__ dinv,
            int2* __restrict__ csr_sw, int E) {
    int e = blockIdx.x * 256 + threadIdx.x;
    if (e >= E) return;
    int s = src[e], d = dst[e];
    int p = atomicAdd(&cursor[d], 1);
    float w = dinv[s] * dinv[d];
    csr_sw[p] = make_int2(s, __builtin_bit_cast(int, w));
}

// ---------- batchnorm column stats (fp32 input), 2-way unrolled grid-stride ----------
__global__ __launch_bounds__(256)
void k_bnstats(const float* __restrict__ x, float* __restrict__ sum, float* __restrict__ sumsq,
               int N, int F) {
    __shared__ float ls[512], lq[512];
    int q   = F >> 2;            // column quads per row
    int t   = threadIdx.x;
    int cq  = t % q;
    int ro  = t / q;
    int rpp = 256 / q;
    int step = gridDim.x * rpp;
    float s0 = 0.f, s1 = 0.f, s2 = 0.f, s3 = 0.f;
    float q0 = 0.f, q1 = 0.f, q2 = 0.f, q3 = 0.f;
    for (int r = blockIdx.x * rpp + ro; r < N; r += 2 * step) {
        float4 v = *(const float4*)&x[(size_t)r * F + cq * 4];
        int r2 = r + step;
        if (r2 < N) {
            float4 u = *(const float4*)&x[(size_t)r2 * F + cq * 4];
            s0 += u.x; s1 += u.y; s2 += u.z; s3 += u.w;
            q0 += u.x * u.x; q1 += u.y * u.y; q2 += u.z * u.z; q3 += u.w * u.w;
        }
        s0 += v.x; s1 += v.y; s2 += v.z; s3 += v.w;
        q0 += v.x * v.x; q1 += v.y * v.y; q2 += v.z * v.z; q3 += v.w * v.w;
    }
    for (int c = t; c < F; c += 256) { ls[c] = 0.f; lq[c] = 0.f; }
    __syncthreads();
    atomicAdd(&ls[cq * 4 + 0], s0); atomicAdd(&ls[cq * 4 + 1], s1);
    atomicAdd(&ls[cq * 4 + 2], s2); atomicAdd(&ls[cq * 4 + 3], s3);
    atomicAdd(&lq[cq * 4 + 0], q0); atomicAdd(&lq[cq * 4 + 1], q1);
    atomicAdd(&lq[cq * 4 + 2], q2); atomicAdd(&lq[cq * 4 + 3], q3);
    __syncthreads();
    for (int c = t; c < F; c += 256) {
        atomicAdd(&sum[c],   ls[c]);
        atomicAdd(&sumsq[c], lq[c]);
    }
}

// ---------- batchnorm column stats on bf16 input (H=256) ----------
__global__ __launch_bounds__(256)
void k_bnstats_b(const unsigned short* __restrict__ x, float* __restrict__ sum,
                 float* __restrict__ sumsq, int N, int H) {
    __shared__ float ls[256], lq[256];
    int t  = threadIdx.x;
    int cg = t & 31;             // 32 col-groups of 8 (H=256)
    int ro = t >> 5;             // 8 rows per pass
    int step = gridDim.x * 8;
    float s[8], q[8];
    #pragma unroll
    for (int j = 0; j < 8; ++j) { s[j] = 0.f; q[j] = 0.f; }
    for (int r = blockIdx.x * 8 + ro; r < N; r += step) {
        shortx8 v = *(const shortx8*)&x[(size_t)r * H + cg * 8];
        #pragma unroll
        for (int j = 0; j < 8; ++j) {
            float f = b2f_s(v[j]);
            s[j] += f; q[j] += f * f;
        }
    }
    ls[t] = 0.f; lq[t] = 0.f;
    __syncthreads();
    #pragma unroll
    for (int j = 0; j < 8; ++j) {
        atomicAdd(&ls[cg * 8 + j], s[j]);
        atomicAdd(&lq[cg * 8 + j], q[j]);
    }
    __syncthreads();
    atomicAdd(&sum[t],   ls[t]);
    atomicAdd(&sumsq[t], lq[t]);
}

__global__ __launch_bounds__(256)
void k_bnfin(const float* __restrict__ sum, const float* __restrict__ sumsq,
             const float* __restrict__ gamma, const float* __restrict__ beta,
             float* __restrict__ a, float* __restrict__ b, int N, int F) {
    int c = blockIdx.x * 256 + threadIdx.x;
    if (c >= F) return;
    float m   = sum[c] / (float)N;
    float var = sumsq[c] / (float)N - m * m;
    float rs  = rsqrtf(var + BN_EPS);
    float aa  = gamma[c] * rs;
    a[c] = aa;
    b[c] = beta[c] - m * aa;
}

// ---------- BN-affine + cast x -> bf16, zero-pad rows [N, Mpad) ----------
__global__ __launch_bounds__(256)
void k_cast_bn(const float* __restrict__ x, const float* __restrict__ a, const float* __restrict__ b,
               unsigned short* __restrict__ xb, int N, int F, int Mpad) {
    int i = blockIdx.x * 256 + threadIdx.x;       // one per 8 elements
    int total = Mpad * (F / 8);
    if (i >= total) return;
    int row = i / (F / 8);
    int col = (i % (F / 8)) * 8;
    shortx8 v;
    if (row < N) {
        float4 x0 = *(const float4*)&x[(size_t)row * F + col];
        float4 x1 = *(const float4*)&x[(size_t)row * F + col + 4];
        float4 a0 = *(const float4*)&a[col];
        float4 a1 = *(const float4*)&a[col + 4];
        float4 b0 = *(const float4*)&b[col];
        float4 b1 = *(const float4*)&b[col + 4];
        v[0] = (short)f2b(x0.x * a0.x + b0.x);
        v[1] = (short)f2b(x0.y * a0.y + b0.y);
        v[2] = (short)f2b(x0.z * a0.z + b0.z);
        v[3] = (short)f2b(x0.w * a0.w + b0.w);
        v[4] = (short)f2b(x1.x * a1.x + b1.x);
        v[5] = (short)f2b(x1.y * a1.y + b1.y);
        v[6] = (short)f2b(x1.z * a1.z + b1.z);
        v[7] = (short)f2b(x1.w * a1.w + b1.w);
    } else {
        #pragma unroll
        for (int j = 0; j < 8; ++j) v[j] = 0;
    }
    *(shortx8*)&xb[(size_t)row * F + col] = v;
}

// ---------- cast + transpose all 4 weights in one launch ----------
__global__ __launch_bounds__(256)
void k_castWT4(const float* __restrict__ W1, const float* __restrict__ W2,
               const float* __restrict__ W3, const float* __restrict__ W4,
               unsigned short* __restrict__ T1, unsigned short* __restrict__ T2,
               unsigned short* __restrict__ T3, unsigned short* __restrict__ T4,
               int F, int H) {
    int i = blockIdx.x * 256 + threadIdx.x;
    int n1 = F * H, n2 = H * H;
    const float* W; unsigned short* T; int K; int j;
    if (i < n1)               { W = W1; T = T1; K = F; j = i; }
    else if (i < n1 + n2)     { W = W2; T = T2; K = H; j = i - n1; }
    else if (i < n1 + 2 * n2) { W = W3; T = T3; K = H; j = i - n1 - n2; }
    else if (i < n1 + 3 * n2) { W = W4; T = T4; K = H; j = i - n1 - 2 * n2; }
    else return;
    int n = j / K, k = j % K;
    T[j] = f2b(W[(size_t)k * H + n]);
}

// ---------- bf16 MFMA GEMM: C[M,NC] = A[M,K] @ Wt[NC,K]^T ----------
__device__ __forceinline__ void glds16(const void* g, void* l) {
    __builtin_amdgcn_global_load_lds(
        (const __attribute__((address_space(1))) unsigned int*)g,
        (__attribute__((address_space(3))) unsigned int*)l, 16, 0, 0);
}

__global__ __launch_bounds__(256)
void k_gemm_bf16(const unsigned short* __restrict__ A, const unsigned short* __restrict__ Bt,
                 unsigned short* __restrict__ C, int K, int NC) {
    __shared__ unsigned short As[128 * 32];
    __shared__ unsigned short Bs[128 * 32];
    int tid  = threadIdx.x;
    int wave = tid >> 6, lane = tid & 63;
    int row0 = blockIdx.x * 128;
    int col0 = blockIdx.y * 128;
    int wr = (wave & 1) * 64;
    int wc = (wave >> 1) * 64;

    floatx4 acc[4][4];
    #pragma unroll
    for (int i = 0; i < 4; i++)
        #pragma unroll
        for (int j = 0; j < 4; j++) acc[i][j] = (floatx4){0.f, 0.f, 0.f, 0.f};

    int cA = tid * 16;
    int cB = cA + 4096;
    const char* Ab = (const char*)A;
    const char* Bb = (const char*)Bt;
    size_t a_off0 = (size_t)(row0 + (cA >> 6)) * K * 2 + (cA & 63);
    size_t a_off1 = (size_t)(row0 + (cB >> 6)) * K * 2 + (cB & 63);
    size_t b_off0 = (size_t)(col0 + (cA >> 6)) * K * 2 + (cA & 63);
    size_t b_off1 = (size_t)(col0 + (cB >> 6)) * K * 2 + (cB & 63);

    int lm  = lane & 15;
    int lk8 = (lane >> 4) * 8;

    for (int ks = 0; ks < K; ks += 32) {
        size_t koff = (size_t)ks * 2;
        glds16(Ab + a_off0 + koff, (char*)As + cA);
        glds16(Ab + a_off1 + koff, (char*)As + cA + 4096);
        glds16(Bb + b_off0 + koff, (char*)Bs + cA);
        glds16(Bb + b_off1 + koff, (char*)Bs + cA + 4096);
        __syncthreads();

        bf16x8 af[4], bfr[4];
        #pragma unroll
        for (int i = 0; i < 4; i++) {
            shortx8 s = *(const shortx8*)&As[(wr + i * 16 + lm) * 32 + lk8];
            af[i] = __builtin_bit_cast(bf16x8, s);
        }
        #pragma unroll
        for (int j = 0; j < 4; j++) {
            shortx8 s = *(const shortx8*)&Bs[(wc + j * 16 + lm) * 32 + lk8];
            bfr[j] = __builtin_bit_cast(bf16x8, s);
        }
        #pragma unroll
        for (int i = 0; i < 4; i++)
            #pragma unroll
            for (int j = 0; j < 4; j++)
                acc[i][j] = __builtin_amdgcn_mfma_f32_16x16x32_bf16(af[i], bfr[j], acc[i][j], 0, 0, 0);
        __syncthreads();
    }

    int crow = row0 + wr + (lane >> 4) * 4;
    int ccol = col0 + wc + lm;
    #pragma unroll
    for (int i = 0; i < 4; i++)
        #pragma unroll
        for (int j = 0; j < 4; j++)
            #pragma unroll
            for (int r = 0; r < 4; r++)
                C[(size_t)(crow + i * 16 + r) * NC + ccol + j * 16] = f2b(acc[i][j][r]);
}

// ---------- CSR gather-aggregation: wave per node, half-wave per edge, 16B row loads ----------
// Lane L<32 handles even-offset edges, L>=32 odd-offset; each half-lane owns 8 features.
__global__ __launch_bounds__(256)
void k_agg(const unsigned short* __restrict__ hin, unsigned short* __restrict__ hout,
           const int* __restrict__ row_ptr, const int2* __restrict__ csr_sw,
           const float* __restrict__ dinv, const float* __restrict__ bias, int N) {
    const int H = 256;
    int node = blockIdx.x * 4 + (threadIdx.x >> 6);
    if (node >= N) return;
    int lane = threadIdx.x & 63;
    int half = lane >> 5;
    int f = (lane & 31) * 8;       // features owned by this lane (both halves own same set)
    float acc[8];
    float di = dinv[node];
    if (half == 0) {
        shortx8 hv = *(const shortx8*)&hin[(size_t)node * H + f];
        float sl = di * di;
        #pragma unroll
        for (int j = 0; j < 8; ++j) acc[j] = b2f_s(hv[j]) * sl;
    } else {
        #pragma unroll
        for (int j = 0; j < 8; ++j) acc[j] = 0.f;
    }
    int e0 = row_ptr[node], e1 = row_ptr[node + 1];
    int e = e0;
    for (; e + 8 <= e1; e += 8) {
        int2 p0 = csr_sw[e + 0 + half];
        int2 p1 = csr_sw[e + 2 + half];
        int2 p2 = csr_sw[e + 4 + half];
        int2 p3 = csr_sw[e + 6 + half];
        shortx8 r0 = *(const shortx8*)&hin[(size_t)p0.x * H + f];
        shortx8 r1 = *(const shortx8*)&hin[(size_t)p1.x * H + f];
        shortx8 r2 = *(const shortx8*)&hin[(size_t)p2.x * H + f];
        shortx8 r3 = *(const shortx8*)&hin[(size_t)p3.x * H + f];
        float w0 = __builtin_bit_cast(float, p0.y);
        float w1 = __builtin_bit_cast(float, p1.y);
        float w2 = __builtin_bit_cast(float, p2.y);
        float w3 = __builtin_bit_cast(float, p3.y);
        #pragma unroll
        for (int j = 0; j < 8; ++j)
            acc[j] += w0 * b2f_s(r0[j]) + w1 * b2f_s(r1[j])
                    + w2 * b2f_s(r2[j]) + w3 * b2f_s(r3[j]);
    }
    for (; e < e1; e += 2) {
        int idx = e + half;
        bool valid = idx < e1;
        int2 pr = csr_sw[valid ? idx : e];
        float w = valid ? __builtin_bit_cast(float, pr.y) : 0.f;
        shortx8 r = *(const shortx8*)&hin[(size_t)pr.x * H + f];
        #pragma unroll
        for (int j = 0; j < 8; ++j) acc[j] += w * b2f_s(r[j]);
    }
    #pragma unroll
    for (int j = 0; j < 8; ++j) acc[j] += __shfl_xor(acc[j], 32, 64);
    if (half == 0) {
        float4 bi0 = *(const float4*)&bias[f];
        float4 bi1 = *(const float4*)&bias[f + 4];
        shortx8 o;
        o[0] = (short)f2b(acc[0] + bi0.x);
        o[1] = (short)f2b(acc[1] + bi0.y);
        o[2] = (short)f2b(acc[2] + bi0.z);
        o[3] = (short)f2b(acc[3] + bi0.w);
        o[4] = (short)f2b(acc[4] + bi1.x);
        o[5] = (short)f2b(acc[5] + bi1.y);
        o[6] = (short)f2b(acc[6] + bi1.z);
        o[7] = (short)f2b(acc[7] + bi1.w);
        *(shortx8*)&hout[(size_t)node * H + f] = o;
    }
}

// ---------- head: BN2 affine + [256x5] dense + sigmoid, 4 nodes per block, bf16 in ----------
__global__ __launch_bounds__(256)
void k_head(const unsigned short* __restrict__ h, const float* __restrict__ a,
            const float* __restrict__ b, const float* __restrict__ Wd,
            const float* __restrict__ bd, float* __restrict__ out, int N) {
    int node = blockIdx.x * 4 + (threadIdx.x >> 6);
    if (node >= N) return;
    int lane = threadIdx.x & 63;
    int f = lane * 4;
    shortx4 hv = *(const shortx4*)&h[(size_t)node * 256 + f];
    float v0 = b2f_s(hv[0]) * a[f + 0] + b[f + 0];
    float v1 = b2f_s(hv[1]) * a[f + 1] + b[f + 1];
    float v2 = b2f_s(hv[2]) * a[f + 2] + b[f + 2];
    float v3 = b2f_s(hv[3]) * a[f + 3] + b[f + 3];
    float s[5];
    #pragma unroll
    for (int j = 0; j < 5; ++j) {
        s[j] = v0 * Wd[(f + 0) * 5 + j] + v1 * Wd[(f + 1) * 5 + j] +
               v2 * Wd[(f + 2) * 5 + j] + v3 * Wd[(f + 3) * 5 + j];
    }
    #pragma unroll
    for (int off = 32; off > 0; off >>= 1) {
        #pragma unroll
        for (int j = 0; j < 5; ++j) s[j] += __shfl_down(s[j], off, 64);
    }
    if (lane == 0) {
        #pragma unroll
        for (int j = 0; j < 5; ++j) {
            float z = s[j] + bd[j];
            out[(size_t)node * 5 + j] = 1.f / (1.f + expf(-z));
        }
    }
}

extern "C" void kernel_launch(void* const* d_in, const int* in_sizes, int n_in,
                              void* d_out, int out_size, void* d_ws, size_t ws_size,
                              hipStream_t stream) {
    const float* x      = (const float*)d_in[0];
    const void*  ei_raw = d_in[1];
    const float* gamma1 = (const float*)d_in[2];
    const float* beta1  = (const float*)d_in[3];
    const float* W1 = (const float*)d_in[4];
    const float* b1 = (const float*)d_in[5];
    const float* W2 = (const float*)d_in[6];
    const float* b2 = (const float*)d_in[7];
    const float* W3 = (const float*)d_in[8];
    const float* b3 = (const float*)d_in[9];
    const float* W4 = (const float*)d_in[10];
    const float* b4 = (const float*)d_in[11];
    const float* gamma2 = (const float*)d_in[12];
    const float* beta2  = (const float*)d_in[13];
    const float* Wd = (const float*)d_in[14];
    const float* bd = (const float*)d_in[15];

    const int F = in_sizes[2];        // 512
    const int N = in_sizes[0] / F;    // 50000
    const int E = in_sizes[1] / 2;    // 800000
    const int H = in_sizes[5];        // 256
    const int Mpad = ((N + 127) / 128) * 128;   // 50048
    const int NB   = (N + 1023) / 1024;         // scan blocks
    float* out = (float*)d_out;

    char* p = (char*)d_ws;
    auto alloc = [&](size_t bytes) {
        void* r = (void*)p;
        p += (bytes + 255) & ~(size_t)255;
        return r;
    };
    int*   flag    = (int*)  alloc(4);
    int*   srcA    = (int*)  alloc((size_t)E * 4);
    int*   dstA    = (int*)  alloc((size_t)E * 4);
    int*   cnt     = (int*)  alloc((size_t)N * 4);
    int*   row_ptr = (int*)  alloc(((size_t)N + 1) * 4);
    int*   cursor  = (int*)  alloc((size_t)N * 4);
    float* dinv    = (float*)alloc((size_t)N * 4);
    int2*  csr_sw  = (int2*) alloc((size_t)E * 8);
    int*   bsum    = (int*)  alloc((size_t)NB * 4);
    float* colsum  = (float*)alloc((size_t)F * 4);
    float* colsq   = (float*)alloc((size_t)F * 4);
    float* bna     = (float*)alloc((size_t)F * 4);
    float* bnb     = (float*)alloc((size_t)F * 4);
    unsigned short* W1t = (unsigned short*)alloc((size_t)F * H * 2);
    unsigned short* W2t = (unsigned short*)alloc((size_t)H * H * 2);
    unsigned short* W3t = (unsigned short*)alloc((size_t)H * H * 2);
    unsigned short* W4t = (unsigned short*)alloc((size_t)H * H * 2);
    unsigned short* xb  = (unsigned short*)alloc((size_t)Mpad * F * 2);
    unsigned short* hbA = (unsigned short*)alloc((size_t)Mpad * H * 2);
    unsigned short* hbB = (unsigned short*)alloc((size_t)Mpad * H * 2);

    hipMemsetAsync(cnt,    0, (size_t)N * 4, stream);
    hipMemsetAsync(colsum, 0, (size_t)F * 4, stream);
    hipMemsetAsync(colsq,  0, (size_t)F * 4, stream);

    // graph build
    int n_check = (E >= 2048) ? 2048 : E;
    k_detect<<<1, 256, 0, stream>>>((const unsigned int*)ei_raw, n_check, flag);
    k_convert<<<(E + 255) / 256, 256, 0, stream>>>(ei_raw, flag, srcA, dstA, E);
    k_count<<<(E + 255) / 256, 256, 0, stream>>>(dstA, cnt, E);
    k_scan_sum<<<NB, 1024, 0, stream>>>(cnt, bsum, N);
    k_scan_part<<<1, 1024, 0, stream>>>(bsum, NB);
    k_scan_final<<<NB, 1024, 0, stream>>>(cnt, bsum, row_ptr, cursor, dinv, N);
    k_fill<<<(E + 255) / 256, 256, 0, stream>>>(srcA, dstA, cursor, dinv, csr_sw, E);

    // BN1 + cast
    k_bnstats<<<1024, 256, 0, stream>>>(x, colsum, colsq, N, F);
    k_bnfin<<<(F + 255) / 256, 256, 0, stream>>>(colsum, colsq, gamma1, beta1, bna, bnb, N, F);
    k_cast_bn<<<(Mpad * (F / 8) + 255) / 256, 256, 0, stream>>>(x, bna, bnb, xb, N, F, Mpad);

    // weight casts (+transpose), single launch
    int tot = F * H + 3 * H * H;
    k_castWT4<<<(tot + 255) / 256, 256, 0, stream>>>(W1, W2, W3, W4, W1t, W2t, W3t, W4t, F, H);

    dim3 gg(Mpad / 128, H / 128);
    int aggb = (N + 3) / 4;
    // conv1
    k_gemm_bf16<<<gg, 256, 0, stream>>>(xb, W1t, hbA, F, H);
    k_agg<<<aggb, 256, 0, stream>>>(hbA, hbB, row_ptr, csr_sw, dinv, b1, N);
    // conv2
    k_gemm_bf16<<<gg, 256, 0, stream>>>(hbB, W2t, hbA, H, H);
    k_agg<<<aggb, 256, 0, stream>>>(hbA, hbB, row_ptr, csr_sw, dinv, b2, N);
    // conv3
    k_gemm_bf16<<<gg, 256, 0, stream>>>(hbB, W3t, hbA, H, H);
    k_agg<<<aggb, 256, 0, stream>>>(hbA, hbB, row_ptr, csr_sw, dinv, b3, N);
    // conv4
    k_gemm_bf16<<<gg, 256, 0, stream>>>(hbB, W4t, hbA, H, H);
    k_agg<<<aggb, 256, 0, stream>>>(hbA, hbB, row_ptr, csr_sw, dinv, b4, N);

    // BN2 + head (bf16 path, no fp32 intermediate)
    hipMemsetAsync(colsum, 0, (size_t)H * 4, stream);
    hipMemsetAsync(colsq,  0, (size_t)H * 4, stream);
    k_bnstats_b<<<512, 256, 0, stream>>>(hbB, colsum, colsq, N, H);
    k_bnfin<<<(H + 255) / 256, 256, 0, stream>>>(colsum, colsq, gamma2, beta2, bna, bnb, N, H);
    k_head<<<(N + 3) / 4, 256, 0, stream>>>(hbB, bna, bnb, Wd, bd, out, N);
}

// Round 5
// 693.406 us; speedup vs baseline: 2.5906x; 1.0280x over previous
//
#include <hip/hip_runtime.h>
#include <math.h>

#define BN_EPS 1e-5f

typedef float floatx4 __attribute__((ext_vector_type(4)));
typedef short shortx4 __attribute__((ext_vector_type(4)));
typedef short shortx8 __attribute__((ext_vector_type(8)));
typedef __bf16 bf16x8 __attribute__((ext_vector_type(8)));

// ---- bf16 helpers (RNE, branch-free; no NaNs in this workload) ----
__device__ __forceinline__ unsigned short f2b(float f) {
    unsigned int u = __builtin_bit_cast(unsigned int, f);
    u += 0x7fffu + ((u >> 16) & 1u);
    return (unsigned short)(u >> 16);
}
__device__ __forceinline__ float b2f(unsigned short s) {
    unsigned int u = ((unsigned int)s) << 16;
    return __builtin_bit_cast(float, u);
}
__device__ __forceinline__ float b2f_s(short s) { return b2f((unsigned short)s); }

// ---------- edge-index layout detection (int32 vs int64 storage) ----------
__global__ __launch_bounds__(256)
void k_detect(const unsigned int* __restrict__ ei, int n_check, int* __restrict__ flag) {
    __shared__ int any;
    if (threadIdx.x == 0) any = 0;
    __syncthreads();
    for (int i = threadIdx.x; i < n_check; i += 256) {
        if (ei[2 * i + 1] != 0u) any = 1;
    }
    __syncthreads();
    if (threadIdx.x == 0) *flag = any;   // 1 => int32 layout, 0 => int64 layout
}

// ---------- convert + degree count fused ----------
__global__ __launch_bounds__(256)
void k_convert(const void* __restrict__ ei_raw, const int* __restrict__ flag,
               int* __restrict__ src, int* __restrict__ dst, int* __restrict__ cnt, int E) {
    int e = blockIdx.x * 256 + threadIdx.x;
    if (e >= E) return;
    int s, d;
    if (*flag) {
        const int* a = (const int*)ei_raw;
        s = a[e]; d = a[E + e];
    } else {
        const long long* a = (const long long*)ei_raw;
        s = (int)a[e]; d = (int)a[E + e];
    }
    src[e] = s;
    dst[e] = d;
    atomicAdd(&cnt[d], 1);
}

// ---------- 3-phase parallel exclusive scan ----------
__global__ __launch_bounds__(1024)
void k_scan_sum(const int* __restrict__ cnt, int* __restrict__ bsum, int N) {
    __shared__ int s[1024];
    int i = blockIdx.x * 1024 + threadIdx.x;
    s[threadIdx.x] = (i < N) ? cnt[i] : 0;
    __syncthreads();
    for (int off = 512; off > 0; off >>= 1) {
        if (threadIdx.x < off) s[threadIdx.x] += s[threadIdx.x + off];
        __syncthreads();
    }
    if (threadIdx.x == 0) bsum[blockIdx.x] = s[0];
}

__global__ __launch_bounds__(1024)
void k_scan_part(int* __restrict__ bsum, int nb) {
    __shared__ int s[1024];
    int t = threadIdx.x;
    int v = (t < nb) ? bsum[t] : 0;
    s[t] = v;
    __syncthreads();
    for (int off = 1; off < 1024; off <<= 1) {
        int tmp = (t >= off) ? s[t - off] : 0;
        __syncthreads();
        s[t] += tmp;
        __syncthreads();
    }
    if (t < nb) bsum[t] = s[t] - v;     // exclusive
}

__global__ __launch_bounds__(1024)
void k_scan_final(const int* __restrict__ cnt, const int* __restrict__ bsum,
                  int* __restrict__ row_ptr, int* __restrict__ cursor,
                  float* __restrict__ dinv, int N) {
    __shared__ int s[1024];
    int b = blockIdx.x, t = threadIdx.x;
    int i = b * 1024 + t;
    int v = (i < N) ? cnt[i] : 0;
    s[t] = v;
    __syncthreads();
    for (int off = 1; off < 1024; off <<= 1) {
        int tmp = (t >= off) ? s[t - off] : 0;
        __syncthreads();
        s[t] += tmp;
        __syncthreads();
    }
    if (i < N) {
        int excl = bsum[b] + s[t] - v;
        row_ptr[i] = excl;
        cursor[i]  = excl;
        dinv[i] = rsqrtf((float)(v + 1));
        if (i == N - 1) row_ptr[N] = excl + v;
    }
}

// ---------- CSR fill: packed (src, weight) pairs ----------
__global__ __launch_bounds__(256)
void k_fill(const int* __restrict__ src, const int* __restrict__ dst,
            int* __restrict__ cursor, const float* __restrict__ dinv,
            int2* __restrict__ csr_sw, int E) {
    int e = blockIdx.x * 256 + threadIdx.x;
    if (e >= E) return;
    int s = src[e], d = dst[e];
    int p = atomicAdd(&cursor[d], 1);
    float w = dinv[s] * dinv[d];
    csr_sw[p] = make_int2(s, __builtin_bit_cast(int, w));
}

// ---------- fused BN1 stats + raw bf16 cast of x (x read ONCE) ----------
// sum8/sumsq8: 8 replicas of F columns each (contention /8).
__global__ __launch_bounds__(256)
void k_bnstats_cast(const float* __restrict__ x, unsigned short* __restrict__ xb,
                    float* __restrict__ sum8, float* __restrict__ sumsq8, int N, int F) {
    __shared__ float ls[512], lq[512];
    int q   = F >> 2;            // 128 column quads
    int t   = threadIdx.x;
    int cq  = t % q;
    int ro  = t / q;
    int rpp = 256 / q;           // 2
    int step = gridDim.x * rpp;
    float s0 = 0.f, s1 = 0.f, s2 = 0.f, s3 = 0.f;
    float q0 = 0.f, q1 = 0.f, q2 = 0.f, q3 = 0.f;
    size_t colb = (size_t)cq * 4;
    for (int r = blockIdx.x * rpp + ro; r < N; r += 4 * step) {
        int rb = r + step, rc = r + 2 * step, rd = r + 3 * step;
        bool ob = rb < N, oc = rc < N, od = rd < N;
        float4 va = *(const float4*)&x[(size_t)r * F + colb];
        float4 vb, vc, vd;
        if (ob) vb = *(const float4*)&x[(size_t)rb * F + colb];
        if (oc) vc = *(const float4*)&x[(size_t)rc * F + colb];
        if (od) vd = *(const float4*)&x[(size_t)rd * F + colb];
        shortx4 o;
        o[0] = (short)f2b(va.x); o[1] = (short)f2b(va.y);
        o[2] = (short)f2b(va.z); o[3] = (short)f2b(va.w);
        *(shortx4*)&xb[(size_t)r * F + colb] = o;
        s0 += va.x; s1 += va.y; s2 += va.z; s3 += va.w;
        q0 += va.x * va.x; q1 += va.y * va.y; q2 += va.z * va.z; q3 += va.w * va.w;
        if (ob) {
            o[0] = (short)f2b(vb.x); o[1] = (short)f2b(vb.y);
            o[2] = (short)f2b(vb.z); o[3] = (short)f2b(vb.w);
            *(shortx4*)&xb[(size_t)rb * F + colb] = o;
            s0 += vb.x; s1 += vb.y; s2 += vb.z; s3 += vb.w;
            q0 += vb.x * vb.x; q1 += vb.y * vb.y; q2 += vb.z * vb.z; q3 += vb.w * vb.w;
        }
        if (oc) {
            o[0] = (short)f2b(vc.x); o[1] = (short)f2b(vc.y);
            o[2] = (short)f2b(vc.z); o[3] = (short)f2b(vc.w);
            *(shortx4*)&xb[(size_t)rc * F + colb] = o;
            s0 += vc.x; s1 += vc.y; s2 += vc.z; s3 += vc.w;
            q0 += vc.x * vc.x; q1 += vc.y * vc.y; q2 += vc.z * vc.z; q3 += vc.w * vc.w;
        }
        if (od) {
            o[0] = (short)f2b(vd.x); o[1] = (short)f2b(vd.y);
            o[2] = (short)f2b(vd.z); o[3] = (short)f2b(vd.w);
            *(shortx4*)&xb[(size_t)rd * F + colb] = o;
            s0 += vd.x; s1 += vd.y; s2 += vd.z; s3 += vd.w;
            q0 += vd.x * vd.x; q1 += vd.y * vd.y; q2 += vd.z * vd.z; q3 += vd.w * vd.w;
        }
    }
    for (int c = t; c < F; c += 256) { ls[c] = 0.f; lq[c] = 0.f; }
    __syncthreads();
    atomicAdd(&ls[cq * 4 + 0], s0); atomicAdd(&ls[cq * 4 + 1], s1);
    atomicAdd(&ls[cq * 4 + 2], s2); atomicAdd(&ls[cq * 4 + 3], s3);
    atomicAdd(&lq[cq * 4 + 0], q0); atomicAdd(&lq[cq * 4 + 1], q1);
    atomicAdd(&lq[cq * 4 + 2], q2); atomicAdd(&lq[cq * 4 + 3], q3);
    __syncthreads();
    int rep = (blockIdx.x & 7) * F;
    for (int c = t; c < F; c += 256) {
        atomicAdd(&sum8[rep + c],   ls[c]);
        atomicAdd(&sumsq8[rep + c], lq[c]);
    }
}

// ---------- batchnorm column stats on bf16 input (H=256), 4 replicas ----------
__global__ __launch_bounds__(256)
void k_bnstats_b(const unsigned short* __restrict__ x, float* __restrict__ sum,
                 float* __restrict__ sumsq, int N, int H) {
    __shared__ float ls[256], lq[256];
    int t  = threadIdx.x;
    int cg = t & 31;
    int ro = t >> 5;
    int step = gridDim.x * 8;
    float s[8], q[8];
    #pragma unroll
    for (int j = 0; j < 8; ++j) { s[j] = 0.f; q[j] = 0.f; }
    for (int r = blockIdx.x * 8 + ro; r < N; r += step) {
        shortx8 v = *(const shortx8*)&x[(size_t)r * H + cg * 8];
        #pragma unroll
        for (int j = 0; j < 8; ++j) {
            float f = b2f_s(v[j]);
            s[j] += f; q[j] += f * f;
        }
    }
    ls[t] = 0.f; lq[t] = 0.f;
    __syncthreads();
    #pragma unroll
    for (int j = 0; j < 8; ++j) {
        atomicAdd(&ls[cg * 8 + j], s[j]);
        atomicAdd(&lq[cg * 8 + j], q[j]);
    }
    __syncthreads();
    int rep = (blockIdx.x & 3) * H;
    atomicAdd(&sum[rep + t],   ls[t]);
    atomicAdd(&sumsq[rep + t], lq[t]);
}

// ---------- finalize BN affine from nrep replicated partials ----------
__global__ __launch_bounds__(256)
void k_bnfin(const float* __restrict__ sum, const float* __restrict__ sumsq,
             const float* __restrict__ gamma, const float* __restrict__ beta,
             float* __restrict__ a, float* __restrict__ b, int N, int F, int nrep) {
    int c = blockIdx.x * 256 + threadIdx.x;
    if (c >= F) return;
    float s = 0.f, ss = 0.f;
    for (int i = 0; i < nrep; ++i) { s += sum[i * F + c]; ss += sumsq[i * F + c]; }
    float m   = s / (float)N;
    float var = ss / (float)N - m * m;
    float rs  = rsqrtf(var + BN_EPS);
    float aa  = gamma[c] * rs;
    a[c] = aa;
    b[c] = beta[c] - m * aa;
}

// ---------- cast + transpose all 4 weights; W1 scaled by BN1 a[k] ----------
__global__ __launch_bounds__(256)
void k_castWT4(const float* __restrict__ W1, const float* __restrict__ W2,
               const float* __restrict__ W3, const float* __restrict__ W4,
               unsigned short* __restrict__ T1, unsigned short* __restrict__ T2,
               unsigned short* __restrict__ T3, unsigned short* __restrict__ T4,
               const float* __restrict__ bna, int F, int H) {
    int i = blockIdx.x * 256 + threadIdx.x;
    int n1 = F * H, n2 = H * H;
    if (i < n1) {
        int n = i / F, k = i % F;
        T1[i] = f2b(W1[(size_t)k * H + n] * bna[k]);
        return;
    }
    const float* W; unsigned short* T; int j;
    if (i < n1 + n2)          { W = W2; T = T2; j = i - n1; }
    else if (i < n1 + 2 * n2) { W = W3; T = T3; j = i - n1 - n2; }
    else if (i < n1 + 3 * n2) { W = W4; T = T4; j = i - n1 - 2 * n2; }
    else return;
    int n = j / H, k = j % H;
    T[j] = f2b(W[(size_t)k * H + n]);
}

// ---------- cvec: c_j = sum_k bnb[k] * W1[k,j]  (BN1 shift folded through GEMM1) ----------
__global__ __launch_bounds__(256)
void k_cvec(const float* __restrict__ W1, const float* __restrict__ bnb,
            float* __restrict__ cvec, int F, int H) {
    int j = threadIdx.x;           // H == 256 == blockDim
    int kslice = F / 8;
    int k0 = blockIdx.x * kslice;
    float s = 0.f;
    for (int k = k0; k < k0 + kslice; ++k)
        s += bnb[k] * W1[(size_t)k * H + j];
    atomicAdd(&cvec[j], s);
}

// ---------- bf16 MFMA GEMM: C[M,NC] = A[M,K] @ Wt[NC,K]^T ----------
__device__ __forceinline__ void glds16(const void* g, void* l) {
    __builtin_amdgcn_global_load_lds(
        (const __attribute__((address_space(1))) unsigned int*)g,
        (__attribute__((address_space(3))) unsigned int*)l, 16, 0, 0);
}

__global__ __launch_bounds__(256)
void k_gemm_bf16(const unsigned short* __restrict__ A, const unsigned short* __restrict__ Bt,
                 unsigned short* __restrict__ C, int K, int NC) {
    __shared__ unsigned short As[128 * 32];
    __shared__ unsigned short Bs[128 * 32];
    int tid  = threadIdx.x;
    int wave = tid >> 6, lane = tid & 63;
    int row0 = blockIdx.x * 128;
    int col0 = blockIdx.y * 128;
    int wr = (wave & 1) * 64;
    int wc = (wave >> 1) * 64;

    floatx4 acc[4][4];
    #pragma unroll
    for (int i = 0; i < 4; i++)
        #pragma unroll
        for (int j = 0; j < 4; j++) acc[i][j] = (floatx4){0.f, 0.f, 0.f, 0.f};

    int cA = tid * 16;
    int cB = cA + 4096;
    const char* Ab = (const char*)A;
    const char* Bb = (const char*)Bt;
    size_t a_off0 = (size_t)(row0 + (cA >> 6)) * K * 2 + (cA & 63);
    size_t a_off1 = (size_t)(row0 + (cB >> 6)) * K * 2 + (cB & 63);
    size_t b_off0 = (size_t)(col0 + (cA >> 6)) * K * 2 + (cA & 63);
    size_t b_off1 = (size_t)(col0 + (cB >> 6)) * K * 2 + (cB & 63);

    int lm  = lane & 15;
    int lk8 = (lane >> 4) * 8;

    for (int ks = 0; ks < K; ks += 32) {
        size_t koff = (size_t)ks * 2;
        glds16(Ab + a_off0 + koff, (char*)As + cA);
        glds16(Ab + a_off1 + koff, (char*)As + cA + 4096);
        glds16(Bb + b_off0 + koff, (char*)Bs + cA);
        glds16(Bb + b_off1 + koff, (char*)Bs + cA + 4096);
        __syncthreads();

        bf16x8 af[4], bfr[4];
        #pragma unroll
        for (int i = 0; i < 4; i++) {
            shortx8 s = *(const shortx8*)&As[(wr + i * 16 + lm) * 32 + lk8];
            af[i] = __builtin_bit_cast(bf16x8, s);
        }
        #pragma unroll
        for (int j = 0; j < 4; j++) {
            shortx8 s = *(const shortx8*)&Bs[(wc + j * 16 + lm) * 32 + lk8];
            bfr[j] = __builtin_bit_cast(bf16x8, s);
        }
        #pragma unroll
        for (int i = 0; i < 4; i++)
            #pragma unroll
            for (int j = 0; j < 4; j++)
                acc[i][j] = __builtin_amdgcn_mfma_f32_16x16x32_bf16(af[i], bfr[j], acc[i][j], 0, 0, 0);
        __syncthreads();
    }

    int crow = row0 + wr + (lane >> 4) * 4;
    int ccol = col0 + wc + lm;
    #pragma unroll
    for (int i = 0; i < 4; i++)
        #pragma unroll
        for (int j = 0; j < 4; j++)
            #pragma unroll
            for (int r = 0; r < 4; r++)
                C[(size_t)(crow + i * 16 + r) * NC + ccol + j * 16] = f2b(acc[i][j][r]);
}

// ---------- CSR gather-aggregation: wave per node, half-wave per edge, 16B row loads ----------
// cvec != null (layer 1): adds wsum_i * cvec_j  (BN1 shift correction through A-hat).
__global__ __launch_bounds__(256)
void k_agg(const unsigned short* __restrict__ hin, unsigned short* __restrict__ hout,
           const int* __restrict__ row_ptr, const int2* __restrict__ csr_sw,
           const float* __restrict__ dinv, const float* __restrict__ bias,
           const float* __restrict__ cvec, int N) {
    const int H = 256;
    int node = blockIdx.x * 4 + (threadIdx.x >> 6);
    if (node >= N) return;
    int lane = threadIdx.x & 63;
    int half = lane >> 5;
    int f = (lane & 31) * 8;
    float acc[8];
    float ws;
    float di = dinv[node];
    if (half == 0) {
        shortx8 hv = *(const shortx8*)&hin[(size_t)node * H + f];
        float sl = di * di;
        ws = sl;
        #pragma unroll
        for (int j = 0; j < 8; ++j) acc[j] = b2f_s(hv[j]) * sl;
    } else {
        ws = 0.f;
        #pragma unroll
        for (int j = 0; j < 8; ++j) acc[j] = 0.f;
    }
    int e0 = row_ptr[node], e1 = row_ptr[node + 1];
    int e = e0;
    for (; e + 8 <= e1; e += 8) {
        int2 p0 = csr_sw[e + 0 + half];
        int2 p1 = csr_sw[e + 2 + half];
        int2 p2 = csr_sw[e + 4 + half];
        int2 p3 = csr_sw[e + 6 + half];
        shortx8 r0 = *(const shortx8*)&hin[(size_t)p0.x * H + f];
        shortx8 r1 = *(const shortx8*)&hin[(size_t)p1.x * H + f];
        shortx8 r2 = *(const shortx8*)&hin[(size_t)p2.x * H + f];
        shortx8 r3 = *(const shortx8*)&hin[(size_t)p3.x * H + f];
        float w0 = __builtin_bit_cast(float, p0.y);
        float w1 = __builtin_bit_cast(float, p1.y);
        float w2 = __builtin_bit_cast(float, p2.y);
        float w3 = __builtin_bit_cast(float, p3.y);
        ws += (w0 + w1) + (w2 + w3);
        #pragma unroll
        for (int j = 0; j < 8; ++j)
            acc[j] += w0 * b2f_s(r0[j]) + w1 * b2f_s(r1[j])
                    + w2 * b2f_s(r2[j]) + w3 * b2f_s(r3[j]);
    }
    for (; e < e1; e += 2) {
        int idx = e + half;
        bool valid = idx < e1;
        int2 pr = csr_sw[valid ? idx : e];
        float w = valid ? __builtin_bit_cast(float, pr.y) : 0.f;
        shortx8 r = *(const shortx8*)&hin[(size_t)pr.x * H + f];
        ws += w;
        #pragma unroll
        for (int j = 0; j < 8; ++j) acc[j] += w * b2f_s(r[j]);
    }
    #pragma unroll
    for (int j = 0; j < 8; ++j) acc[j] += __shfl_xor(acc[j], 32, 64);
    ws += __shfl_xor(ws, 32, 64);
    if (half == 0) {
        float4 bi0 = *(const float4*)&bias[f];
        float4 bi1 = *(const float4*)&bias[f + 4];
        if (cvec) {
            float4 c0 = *(const float4*)&cvec[f];
            float4 c1 = *(const float4*)&cvec[f + 4];
            bi0.x += ws * c0.x; bi0.y += ws * c0.y;
            bi0.z += ws * c0.z; bi0.w += ws * c0.w;
            bi1.x += ws * c1.x; bi1.y += ws * c1.y;
            bi1.z += ws * c1.z; bi1.w += ws * c1.w;
        }
        shortx8 o;
        o[0] = (short)f2b(acc[0] + bi0.x);
        o[1] = (short)f2b(acc[1] + bi0.y);
        o[2] = (short)f2b(acc[2] + bi0.z);
        o[3] = (short)f2b(acc[3] + bi0.w);
        o[4] = (short)f2b(acc[4] + bi1.x);
        o[5] = (short)f2b(acc[5] + bi1.y);
        o[6] = (short)f2b(acc[6] + bi1.z);
        o[7] = (short)f2b(acc[7] + bi1.w);
        *(shortx8*)&hout[(size_t)node * H + f] = o;
    }
}

// ---------- head: BN2 affine + [256x5] dense + sigmoid, 4 nodes per block ----------
__global__ __launch_bounds__(256)
void k_head(const unsigned short* __restrict__ h, const float* __restrict__ a,
            const float* __restrict__ b, const float* __restrict__ Wd,
            const float* __restrict__ bd, float* __restrict__ out, int N) {
    int node = blockIdx.x * 4 + (threadIdx.x >> 6);
    if (node >= N) return;
    int lane = threadIdx.x & 63;
    int f = lane * 4;
    shortx4 hv = *(const shortx4*)&h[(size_t)node * 256 + f];
    float v0 = b2f_s(hv[0]) * a[f + 0] + b[f + 0];
    float v1 = b2f_s(hv[1]) * a[f + 1] + b[f + 1];
    float v2 = b2f_s(hv[2]) * a[f + 2] + b[f + 2];
    float v3 = b2f_s(hv[3]) * a[f + 3] + b[f + 3];
    float s[5];
    #pragma unroll
    for (int j = 0; j < 5; ++j) {
        s[j] = v0 * Wd[(f + 0) * 5 + j] + v1 * Wd[(f + 1) * 5 + j] +
               v2 * Wd[(f + 2) * 5 + j] + v3 * Wd[(f + 3) * 5 + j];
    }
    #pragma unroll
    for (int off = 32; off > 0; off >>= 1) {
        #pragma unroll
        for (int j = 0; j < 5; ++j) s[j] += __shfl_down(s[j], off, 64);
    }
    if (lane == 0) {
        #pragma unroll
        for (int j = 0; j < 5; ++j) {
            float z = s[j] + bd[j];
            out[(size_t)node * 5 + j] = 1.f / (1.f + expf(-z));
        }
    }
}

extern "C" void kernel_launch(void* const* d_in, const int* in_sizes, int n_in,
                              void* d_out, int out_size, void* d_ws, size_t ws_size,
                              hipStream_t stream) {
    const float* x      = (const float*)d_in[0];
    const void*  ei_raw = d_in[1];
    const float* gamma1 = (const float*)d_in[2];
    const float* beta1  = (const float*)d_in[3];
    const float* W1 = (const float*)d_in[4];
    const float* b1 = (const float*)d_in[5];
    const float* W2 = (const float*)d_in[6];
    const float* b2 = (const float*)d_in[7];
    const float* W3 = (const float*)d_in[8];
    const float* b3 = (const float*)d_in[9];
    const float* W4 = (const float*)d_in[10];
    const float* b4 = (const float*)d_in[11];
    const float* gamma2 = (const float*)d_in[12];
    const float* beta2  = (const float*)d_in[13];
    const float* Wd = (const float*)d_in[14];
    const float* bd = (const float*)d_in[15];

    const int F = in_sizes[2];        // 512
    const int N = in_sizes[0] / F;    // 50000
    const int E = in_sizes[1] / 2;    // 800000
    const int H = in_sizes[5];        // 256
    const int Mpad = ((N + 127) / 128) * 128;   // 50048
    const int NB   = (N + 1023) / 1024;
    float* out = (float*)d_out;

    char* p = (char*)d_ws;
    auto alloc = [&](size_t bytes) {
        void* r = (void*)p;
        p += (bytes + 255) & ~(size_t)255;
        return r;
    };
    int*   flag    = (int*)  alloc(4);
    int*   srcA    = (int*)  alloc((size_t)E * 4);
    int*   dstA    = (int*)  alloc((size_t)E * 4);
    // ---- contiguous zero-init group: [cnt | colsum8 | colsq8 | colsum2 | colsq2 | cvec] ----
    char*  zstart  = p;
    int*   cnt     = (int*)  alloc((size_t)N * 4);
    float* colsum8 = (float*)alloc((size_t)8 * F * 4);
    float* colsq8  = (float*)alloc((size_t)8 * F * 4);
    float* colsum2 = (float*)alloc((size_t)4 * H * 4);
    float* colsq2  = (float*)alloc((size_t)4 * H * 4);
    float* cvec    = (float*)alloc((size_t)H * 4);
    size_t zbytes  = (size_t)(p - zstart);
    int*   row_ptr = (int*)  alloc(((size_t)N + 1) * 4);
    int*   cursor  = (int*)  alloc((size_t)N * 4);
    float* dinv    = (float*)alloc((size_t)N * 4);
    int2*  csr_sw  = (int2*) alloc((size_t)E * 8);
    int*   bsum    = (int*)  alloc((size_t)NB * 4);
    float* bna     = (float*)alloc((size_t)F * 4);
    float* bnb     = (float*)alloc((size_t)F * 4);
    unsigned short* W1t = (unsigned short*)alloc((size_t)F * H * 2);
    unsigned short* W2t = (unsigned short*)alloc((size_t)H * H * 2);
    unsigned short* W3t = (unsigned short*)alloc((size_t)H * H * 2);
    unsigned short* W4t = (unsigned short*)alloc((size_t)H * H * 2);
    unsigned short* xb  = (unsigned short*)alloc((size_t)Mpad * F * 2);
    unsigned short* hbA = (unsigned short*)alloc((size_t)Mpad * H * 2);
    unsigned short* hbB = (unsigned short*)alloc((size_t)Mpad * H * 2);

    hipMemsetAsync(zstart, 0, zbytes, stream);
    // zero bf16 pad rows of xb
    hipMemsetAsync(xb + (size_t)N * F, 0, (size_t)(Mpad - N) * F * 2, stream);

    // graph build
    int n_check = (E >= 2048) ? 2048 : E;
    k_detect<<<1, 256, 0, stream>>>((const unsigned int*)ei_raw, n_check, flag);
    k_convert<<<(E + 255) / 256, 256, 0, stream>>>(ei_raw, flag, srcA, dstA, cnt, E);
    k_scan_sum<<<NB, 1024, 0, stream>>>(cnt, bsum, N);
    k_scan_part<<<1, 1024, 0, stream>>>(bsum, NB);
    k_scan_final<<<NB, 1024, 0, stream>>>(cnt, bsum, row_ptr, cursor, dinv, N);
    k_fill<<<(E + 255) / 256, 256, 0, stream>>>(srcA, dstA, cursor, dinv, csr_sw, E);

    // BN1 stats + raw cast (single pass over x)
    k_bnstats_cast<<<2048, 256, 0, stream>>>(x, xb, colsum8, colsq8, N, F);
    k_bnfin<<<(F + 255) / 256, 256, 0, stream>>>(colsum8, colsq8, gamma1, beta1, bna, bnb, N, F, 8);

    // weight casts (W1 scaled by bna) + cvec = bnb^T @ W1
    int tot = F * H + 3 * H * H;
    k_castWT4<<<(tot + 255) / 256, 256, 0, stream>>>(W1, W2, W3, W4, W1t, W2t, W3t, W4t, bna, F, H);
    k_cvec<<<8, 256, 0, stream>>>(W1, bnb, cvec, F, H);

    dim3 gg(Mpad / 128, H / 128);
    int aggb = (N + 3) / 4;
    // conv1 (BN1 folded: xb raw, W1t pre-scaled, cvec correction via wsum)
    k_gemm_bf16<<<gg, 256, 0, stream>>>(xb, W1t, hbA, F, H);
    k_agg<<<aggb, 256, 0, stream>>>(hbA, hbB, row_ptr, csr_sw, dinv, b1, cvec, N);
    // conv2
    k_gemm_bf16<<<gg, 256, 0, stream>>>(hbB, W2t, hbA, H, H);
    k_agg<<<aggb, 256, 0, stream>>>(hbA, hbB, row_ptr, csr_sw, dinv, b2, nullptr, N);
    // conv3
    k_gemm_bf16<<<gg, 256, 0, stream>>>(hbB, W3t, hbA, H, H);
    k_agg<<<aggb, 256, 0, stream>>>(hbA, hbB, row_ptr, csr_sw, dinv, b3, nullptr, N);
    // conv4
    k_gemm_bf16<<<gg, 256, 0, stream>>>(hbB, W4t, hbA, H, H);
    k_agg<<<aggb, 256, 0, stream>>>(hbA, hbB, row_ptr, csr_sw, dinv, b4, nullptr, N);

    // BN2 + head
    k_bnstats_b<<<1024, 256, 0, stream>>>(hbB, colsum2, colsq2, N, H);
    k_bnfin<<<(H + 255) / 256, 256, 0, stream>>>(colsum2, colsq2, gamma2, beta2, bna, bnb, N, H, 4);
    k_head<<<(N + 3) / 4, 256, 0, stream>>>(hbB, bna, bnb, Wd, bd, out, N);
}